// Round 4
// baseline (835.990 us; speedup 1.0000x reference)
//
#include <hip/hip_runtime.h>
#include <math.h>

// GAT 3-layer forward on MI355X.
// N=50000 nodes, E=850000 edges (incl self loops), IN=128, HID=OUT=32, HEADS=(4,4,6).
// GEMMs via split-f16 MFMA (hi/lo, 3 mfma). feat stored f16 for the edge gather
// (softmax logits el/er stay fp32 -> attention weights unaffected by feat quantization).

typedef _Float16 v8h __attribute__((ext_vector_type(8)));
typedef float f32x4 __attribute__((ext_vector_type(4)));

// ---------------- CSR build (by dst) ----------------

__global__ void hist_kernel(const int* __restrict__ dst, int E, int* __restrict__ deg) {
    int i = blockIdx.x * blockDim.x + threadIdx.x;
    if (i < E) atomicAdd(&deg[dst[i]], 1);
}

__global__ void scan_kernel(const int* __restrict__ deg, int* __restrict__ row_start, int n) {
    const int T = 1024;
    __shared__ int sums[T];
    int t = threadIdx.x;
    int chunk = (n + T - 1) / T;
    int begin = t * chunk;
    int finish = begin + chunk; if (finish > n) finish = n;
    int s = 0;
    for (int i = begin; i < finish; i++) s += deg[i];
    sums[t] = s;
    __syncthreads();
    for (int off = 1; off < T; off <<= 1) {
        int u = (t >= off) ? sums[t - off] : 0;
        __syncthreads();
        sums[t] += u;
        __syncthreads();
    }
    int base = (t == 0) ? 0 : sums[t - 1];
    for (int i = begin; i < finish; i++) { row_start[i] = base; base += deg[i]; }
    if (t == T - 1) row_start[n] = sums[T - 1];
}

__global__ void fill_kernel(const int* __restrict__ src, const int* __restrict__ dst, int E,
                            const int* __restrict__ row_start, int* __restrict__ cursor,
                            int* __restrict__ csr_src) {
    int i = blockIdx.x * blockDim.x + threadIdx.x;
    if (i < E) {
        int d = dst[i];
        int pos = atomicAdd(&cursor[d], 1);
        csr_src[row_start[d] + pos] = src[i];
    }
}

// ---------------- weight transpose + f16 hi/lo split (once per call) ----------------
// n-major [c][128] f16. W1h@0 W1l@16384 W2h@32768 W2l@49152
// L3 combined (cols 0..191 = W3, 192..383 = resW3): hi@65536, lo@114688.

__global__ void wsplit_all(const float* __restrict__ W1, const float* __restrict__ W2,
                           const float* __restrict__ W3, const float* __restrict__ Wr,
                           _Float16* __restrict__ o) {
    int i = blockIdx.x * blockDim.x + threadIdx.x;
    if (i >= 81920) return;
    float v; int ohi, e, stride;
    if (i < 16384) {
        e = i; int c = e >> 7, k = e & 127;
        v = W1[(size_t)k * 128 + c]; ohi = 0; stride = 16384;
    } else if (i < 32768) {
        e = i - 16384; int c = e >> 7, k = e & 127;
        v = W2[(size_t)k * 128 + c]; ohi = 32768; stride = 16384;
    } else {
        e = i - 32768; int c = e >> 7, k = e & 127;
        v = (c < 192) ? W3[(size_t)k * 192 + c] : Wr[(size_t)k * 192 + (c - 192)];
        ohi = 65536; stride = 49152;
    }
    _Float16 hv = (_Float16)v;
    o[ohi + e] = hv;
    o[ohi + stride + e] = (_Float16)(v - (float)hv);
}

// ---------------- MFMA fc (+ attention logits) ----------------
// Block: 256 threads = 4 waves; M-tile 64 rows (16/wave); CC output cols.
// Cols [0,SPLIT) -> feat_out (f16, stride SPLIT); cols [SPLIT,CC) -> res_out (fp32).
// el/er (fp32, from fp32 accumulators) over the first H*32 cols if ATT.

template <int CC, int H, bool ATT, int SPLIT>
__global__ __launch_bounds__(256) void mfma_fc(
    const float* __restrict__ hsrc, const _Float16* __restrict__ Bhi,
    const float* __restrict__ al, const float* __restrict__ ar,
    _Float16* __restrict__ feat_out, float* __restrict__ res_out,
    float* __restrict__ el, float* __restrict__ er, int N) {
    constexpr int TILES = CC / 16;
    constexpr int AST = 128 + 8;
    __shared__ _Float16 a_hi[64 * AST];
    __shared__ _Float16 a_lo[64 * AST];

    const _Float16* __restrict__ Blo = Bhi + (size_t)CC * 128;
    int m0 = blockIdx.x * 64;
    int t = threadIdx.x;

    for (int i = t; i < 64 * 32; i += 256) {
        int r = i >> 5;
        int c4 = (i & 31) << 2;
        float4 v = make_float4(0.f, 0.f, 0.f, 0.f);
        int m = m0 + r;
        if (m < N) v = *(const float4*)(hsrc + (size_t)m * 128 + c4);
        _Float16* ph = a_hi + r * AST + c4;
        _Float16* pl = a_lo + r * AST + c4;
        float vv[4] = {v.x, v.y, v.z, v.w};
        #pragma unroll
        for (int q = 0; q < 4; q++) {
            _Float16 hh = (_Float16)vv[q];
            ph[q] = hh;
            pl[q] = (_Float16)(vv[q] - (float)hh);
        }
    }
    __syncthreads();

    int wave = t >> 6;
    int lane = t & 63;
    int ln = lane & 15;
    int quad = lane >> 4;

    f32x4 acc[TILES];
    #pragma unroll
    for (int i = 0; i < TILES; i++) acc[i] = (f32x4){0.f, 0.f, 0.f, 0.f};

    const _Float16* arow_h = a_hi + (wave * 16 + ln) * AST;
    const _Float16* arow_l = a_lo + (wave * 16 + ln) * AST;

    #pragma unroll
    for (int k0 = 0; k0 < 128; k0 += 32) {
        v8h ah = *(const v8h*)(arow_h + k0 + quad * 8);
        v8h alo = *(const v8h*)(arow_l + k0 + quad * 8);
        #pragma unroll 4
        for (int tt = 0; tt < TILES; tt++) {
            const _Float16* bp = Bhi + (size_t)(tt * 16 + ln) * 128 + k0 + quad * 8;
            v8h bh = *(const v8h*)bp;
            v8h bl = *(const v8h*)(Blo + ((size_t)(tt * 16 + ln) * 128 + k0 + quad * 8));
            acc[tt] = __builtin_amdgcn_mfma_f32_16x16x32_f16(alo, bh, acc[tt], 0, 0, 0);
            acc[tt] = __builtin_amdgcn_mfma_f32_16x16x32_f16(ah, bl, acc[tt], 0, 0, 0);
            acc[tt] = __builtin_amdgcn_mfma_f32_16x16x32_f16(ah, bh, acc[tt], 0, 0, 0);
        }
    }

    // epilogue: C/D layout col=lane&15, row=quad*4+reg
    #pragma unroll
    for (int tt = 0; tt < TILES; tt++) {
        int n = tt * 16 + ln;
        #pragma unroll
        for (int r = 0; r < 4; r++) {
            int m = m0 + wave * 16 + quad * 4 + r;
            if (m < N) {
                if (tt * 16 < SPLIT) {
                    feat_out[(size_t)m * SPLIT + n] = (_Float16)acc[tt][r];
                } else {
                    if constexpr (CC > SPLIT)
                        res_out[(size_t)m * (CC - SPLIT) + (n - SPLIT)] = acc[tt][r];
                }
            }
        }
    }
    if constexpr (ATT) {
        #pragma unroll
        for (int hg = 0; hg < H; hg++) {
            float a0 = al[hg * 32 + ln], a1 = al[hg * 32 + 16 + ln];
            float r0 = ar[hg * 32 + ln], r1 = ar[hg * 32 + 16 + ln];
            #pragma unroll
            for (int r = 0; r < 4; r++) {
                float pl = acc[2 * hg][r] * a0 + acc[2 * hg + 1][r] * a1;
                float pr = acc[2 * hg][r] * r0 + acc[2 * hg + 1][r] * r1;
                #pragma unroll
                for (int off = 1; off < 16; off <<= 1) {
                    pl += __shfl_xor(pl, off);
                    pr += __shfl_xor(pr, off);
                }
                int m = m0 + wave * 16 + quad * 4 + r;
                if (ln == 0 && m < N) {
                    el[(size_t)m * H + hg] = pl;
                    er[(size_t)m * H + hg] = pr;
                }
            }
        }
    }
}

// ---------------- single-pass per-node edge softmax + aggregate ----------------
// One block per node, one thread per output dim. feat gathered as f16 (half bytes);
// logits/denoms fp32 -> attention weights unaffected by feat quantization.

template <int H, bool RELU, bool MEAN>
__global__ void gat_agg(const _Float16* __restrict__ feat, const float* __restrict__ el,
                        const float* __restrict__ er, const int* __restrict__ row_start,
                        const int* __restrict__ csr_src, const float* __restrict__ bias,
                        const float* __restrict__ residual, float* __restrict__ out, int N) {
    constexpr int ROW = H * 32;
    constexpr int CHUNK = 128;
    __shared__ int   s_src[CHUNK];
    __shared__ float s_w[CHUNK][H];
    __shared__ float s_er[H], s_m[H], s_d[H], s_scale[H];
    __shared__ float s_red[MEAN ? ROW : 1];

    int n = blockIdx.x;
    int t = threadIdx.x;       // output dim: h*32 + d
    int h = t >> 5;

    int start = row_start[n];
    int end   = row_start[n + 1];

    if (t < H) {
        s_er[t] = er[(size_t)n * H + t];
        s_m[t]  = -INFINITY;
        s_d[t]  = 0.f;
    }
    __syncthreads();

    float acc = 0.f;
    for (int cs = start; cs < end; cs += CHUNK) {
        int c = end - cs; if (c > CHUNK) c = CHUNK;

        for (int i = t; i < c; i += ROW) s_src[i] = csr_src[cs + i];
        __syncthreads();

        for (int i = t; i < c * H; i += ROW) {
            int j = i / H, hh = i - j * H;
            float e = el[(size_t)s_src[j] * H + hh] + s_er[hh];
            s_w[j][hh] = (e >= 0.f) ? e : 0.2f * e;
        }
        __syncthreads();

        if (t < H) {
            float mold = s_m[t];
            float mnew = mold;
            for (int j = 0; j < c; j++) mnew = fmaxf(mnew, s_w[j][t]);
            float sc = __expf(mold - mnew);
            float d = s_d[t] * sc;
            for (int j = 0; j < c; j++) {
                float w = __expf(s_w[j][t] - mnew);
                s_w[j][t] = w;
                d += w;
            }
            s_m[t] = mnew; s_d[t] = d; s_scale[t] = sc;
        }
        __syncthreads();

        acc *= s_scale[h];

        int j = 0;
        for (; j + 8 <= c; j += 8) {
            float fv[8], wv[8];
            #pragma unroll
            for (int q = 0; q < 8; q++) {
                int s = s_src[j + q];
                fv[q] = (float)feat[(size_t)s * ROW + t];
                wv[q] = s_w[j + q][h];
            }
            #pragma unroll
            for (int q = 0; q < 8; q++) acc += wv[q] * fv[q];
        }
        for (; j < c; j++) acc += s_w[j][h] * (float)feat[(size_t)s_src[j] * ROW + t];
        __syncthreads();
    }

    float rst = acc / fmaxf(s_d[h], 1e-9f);
    rst += bias[t];
    if (residual) rst += residual[(size_t)n * ROW + t];
    if (RELU) rst = fmaxf(rst, 0.f);

    if (!MEAN) {
        out[(size_t)n * ROW + t] = rst;
    } else {
        s_red[t] = rst;
        __syncthreads();
        if (t < 32) {
            float v = 0.f;
            #pragma unroll
            for (int hh = 0; hh < H; hh++) v += s_red[hh * 32 + t];
            out[(size_t)n * 32 + t] = v * (1.0f / H);
        }
    }
}

// ---------------- launch ----------------

extern "C" void kernel_launch(void* const* d_in, const int* in_sizes, int n_in,
                              void* d_out, int out_size, void* d_ws, size_t ws_size,
                              hipStream_t stream) {
    const float* x    = (const float*)d_in[0];
    const int*   src  = (const int*)d_in[1];
    const int*   dst  = (const int*)d_in[2];
    const float* W1   = (const float*)d_in[3];
    const float* al1  = (const float*)d_in[4];
    const float* ar1  = (const float*)d_in[5];
    const float* b1   = (const float*)d_in[6];
    const float* W2   = (const float*)d_in[7];
    const float* al2  = (const float*)d_in[8];
    const float* ar2  = (const float*)d_in[9];
    const float* b2   = (const float*)d_in[10];
    const float* W3   = (const float*)d_in[11];
    const float* al3  = (const float*)d_in[12];
    const float* ar3  = (const float*)d_in[13];
    const float* b3   = (const float*)d_in[14];
    const float* resW3= (const float*)d_in[15];
    float* out = (float*)d_out;

    const int N = in_sizes[0] / 128;
    const int E = in_sizes[1];

    // workspace layout
    float* fws  = (float*)d_ws;
    float* h1v  = fws;                          // N*128
    float* h2v  = h1v + (size_t)N * 128;        // N*128
    float* res3 = h2v + (size_t)N * 128;        // N*192
    float* elb  = res3 + (size_t)N * 192;       // N*6
    float* erb  = elb + (size_t)N * 6;          // N*6
    _Float16* feat_h = (_Float16*)(erb + (size_t)N * 6);  // N*192 f16
    _Float16* wts = feat_h + (size_t)N * 192;   // 163840 f16
    int* deg       = (int*)(wts + 163840);         // N
    int* row_start = deg + N;                      // N+1
    int* csr_src   = row_start + (N + 1);          // E

    const _Float16* W1h = wts;
    const _Float16* W2h = wts + 32768;
    const _Float16* L3h = wts + 65536;

    // ---- CSR build (by dst) + weight split ----
    hipMemsetAsync(deg, 0, (size_t)N * sizeof(int), stream);
    hist_kernel<<<dim3((E + 255) / 256), dim3(256), 0, stream>>>(dst, E, deg);
    scan_kernel<<<dim3(1), dim3(1024), 0, stream>>>(deg, row_start, N);
    hipMemsetAsync(deg, 0, (size_t)N * sizeof(int), stream);
    fill_kernel<<<dim3((E + 255) / 256), dim3(256), 0, stream>>>(src, dst, E, row_start, deg, csr_src);
    wsplit_all<<<dim3(320), dim3(256), 0, stream>>>(W1, W2, W3, resW3, wts);

    dim3 mb((N + 63) / 64);

    // ---- Layer 1 ----
    mfma_fc<128, 4, true, 128><<<mb, dim3(256), 0, stream>>>(
        x, W1h, al1, ar1, feat_h, nullptr, elb, erb, N);
    gat_agg<4, true, false><<<dim3(N), dim3(128), 0, stream>>>(
        feat_h, elb, erb, row_start, csr_src, b1, nullptr, h1v, N);

    // ---- Layer 2 ----
    mfma_fc<128, 4, true, 128><<<mb, dim3(256), 0, stream>>>(
        h1v, W2h, al2, ar2, feat_h, nullptr, elb, erb, N);
    gat_agg<4, true, false><<<dim3(N), dim3(128), 0, stream>>>(
        feat_h, elb, erb, row_start, csr_src, b2, h1v, h2v, N);

    // ---- Layer 3 (W3 + resW3 fused: cols 0..191 feat f16, 192..383 res fp32) ----
    mfma_fc<384, 6, true, 192><<<mb, dim3(256), 0, stream>>>(
        h2v, L3h, al3, ar3, feat_h, res3, elb, erb, N);
    gat_agg<6, false, true><<<dim3(N), dim3(192), 0, stream>>>(
        feat_h, elb, erb, row_start, csr_src, b3, res3, out, N);
}

// Round 5
// 726.910 us; speedup vs baseline: 1.1501x; 1.1501x over previous
//
#include <hip/hip_runtime.h>
#include <math.h>

// GAT 3-layer forward on MI355X.
// N=50000 nodes, E=850000 edges (incl self loops), IN=128, HID=OUT=32, HEADS=(4,4,6).
// GEMMs via split-f16 MFMA (hi/lo, 3 mfma), FULLY unrolled tile loop (partial unroll
// dynamically indexes acc[] -> scratch spill, 445MB of spill traffic in round 4).
// feat stored f16 for the edge gather; logits el/er stay fp32.

typedef _Float16 v8h __attribute__((ext_vector_type(8)));
typedef float f32x4 __attribute__((ext_vector_type(4)));

// ---------------- CSR build (by dst) ----------------

__global__ void hist_kernel(const int* __restrict__ dst, int E, int* __restrict__ deg) {
    int i = blockIdx.x * blockDim.x + threadIdx.x;
    if (i < E) atomicAdd(&deg[dst[i]], 1);
}

__global__ void scan_kernel(const int* __restrict__ deg, int* __restrict__ row_start, int n) {
    const int T = 1024;
    __shared__ int sums[T];
    int t = threadIdx.x;
    int chunk = (n + T - 1) / T;
    int begin = t * chunk;
    int finish = begin + chunk; if (finish > n) finish = n;
    int s = 0;
    for (int i = begin; i < finish; i++) s += deg[i];
    sums[t] = s;
    __syncthreads();
    for (int off = 1; off < T; off <<= 1) {
        int u = (t >= off) ? sums[t - off] : 0;
        __syncthreads();
        sums[t] += u;
        __syncthreads();
    }
    int base = (t == 0) ? 0 : sums[t - 1];
    for (int i = begin; i < finish; i++) { row_start[i] = base; base += deg[i]; }
    if (t == T - 1) row_start[n] = sums[T - 1];
}

__global__ void fill_kernel(const int* __restrict__ src, const int* __restrict__ dst, int E,
                            const int* __restrict__ row_start, int* __restrict__ cursor,
                            int* __restrict__ csr_src) {
    int i = blockIdx.x * blockDim.x + threadIdx.x;
    if (i < E) {
        int d = dst[i];
        int pos = atomicAdd(&cursor[d], 1);
        csr_src[row_start[d] + pos] = src[i];
    }
}

// ---------------- weight transpose + f16 hi/lo split (once per call) ----------------
// n-major [c][128] f16. W1h@0 W1l@16384 W2h@32768 W2l@49152
// L3 combined (cols 0..191 = W3, 192..383 = resW3): hi@65536, lo@114688.

__global__ void wsplit_all(const float* __restrict__ W1, const float* __restrict__ W2,
                           const float* __restrict__ W3, const float* __restrict__ Wr,
                           _Float16* __restrict__ o) {
    int i = blockIdx.x * blockDim.x + threadIdx.x;
    if (i >= 81920) return;
    float v; int ohi, e, stride;
    if (i < 16384) {
        e = i; int c = e >> 7, k = e & 127;
        v = W1[(size_t)k * 128 + c]; ohi = 0; stride = 16384;
    } else if (i < 32768) {
        e = i - 16384; int c = e >> 7, k = e & 127;
        v = W2[(size_t)k * 128 + c]; ohi = 32768; stride = 16384;
    } else {
        e = i - 32768; int c = e >> 7, k = e & 127;
        v = (c < 192) ? W3[(size_t)k * 192 + c] : Wr[(size_t)k * 192 + (c - 192)];
        ohi = 65536; stride = 49152;
    }
    _Float16 hv = (_Float16)v;
    o[ohi + e] = hv;
    o[ohi + stride + e] = (_Float16)(v - (float)hv);
}

// ---------------- MFMA fc (+ attention logits) ----------------
// Block: 256 threads = 4 waves; M-tile 64 rows (16/wave); CC output cols.
// F16OUT: write feat f16 (stride CC); else write fp32 res (stride CC).
// tt loop MUST stay fully unrolled (static acc indexing -> registers).

template <int CC, int H, bool ATT, bool F16OUT>
__global__ __launch_bounds__(256) void mfma_fc(
    const float* __restrict__ hsrc,
    const _Float16* __restrict__ Bhi, const _Float16* __restrict__ Blo,
    const float* __restrict__ al, const float* __restrict__ ar,
    _Float16* __restrict__ feat_out, float* __restrict__ res_out,
    float* __restrict__ el, float* __restrict__ er, int N) {
    constexpr int TILES = CC / 16;
    constexpr int AST = 128 + 8;
    __shared__ _Float16 a_hi[64 * AST];
    __shared__ _Float16 a_lo[64 * AST];

    int m0 = blockIdx.x * 64;
    int t = threadIdx.x;

    for (int i = t; i < 64 * 32; i += 256) {
        int r = i >> 5;
        int c4 = (i & 31) << 2;
        float4 v = make_float4(0.f, 0.f, 0.f, 0.f);
        int m = m0 + r;
        if (m < N) v = *(const float4*)(hsrc + (size_t)m * 128 + c4);
        _Float16* ph = a_hi + r * AST + c4;
        _Float16* pl = a_lo + r * AST + c4;
        float vv[4] = {v.x, v.y, v.z, v.w};
        #pragma unroll
        for (int q = 0; q < 4; q++) {
            _Float16 hh = (_Float16)vv[q];
            ph[q] = hh;
            pl[q] = (_Float16)(vv[q] - (float)hh);
        }
    }
    __syncthreads();

    int wave = t >> 6;
    int lane = t & 63;
    int ln = lane & 15;
    int quad = lane >> 4;

    f32x4 acc[TILES];
    #pragma unroll
    for (int i = 0; i < TILES; i++) acc[i] = (f32x4){0.f, 0.f, 0.f, 0.f};

    const _Float16* arow_h = a_hi + (wave * 16 + ln) * AST;
    const _Float16* arow_l = a_lo + (wave * 16 + ln) * AST;

    #pragma unroll
    for (int k0 = 0; k0 < 128; k0 += 32) {
        v8h ah = *(const v8h*)(arow_h + k0 + quad * 8);
        v8h alo = *(const v8h*)(arow_l + k0 + quad * 8);
        #pragma unroll
        for (int tt = 0; tt < TILES; tt++) {
            size_t boff = (size_t)(tt * 16 + ln) * 128 + k0 + quad * 8;
            v8h bh = *(const v8h*)(Bhi + boff);
            v8h bl = *(const v8h*)(Blo + boff);
            acc[tt] = __builtin_amdgcn_mfma_f32_16x16x32_f16(alo, bh, acc[tt], 0, 0, 0);
            acc[tt] = __builtin_amdgcn_mfma_f32_16x16x32_f16(ah, bl, acc[tt], 0, 0, 0);
            acc[tt] = __builtin_amdgcn_mfma_f32_16x16x32_f16(ah, bh, acc[tt], 0, 0, 0);
        }
    }

    // epilogue: C/D layout col=lane&15, row=quad*4+reg
    #pragma unroll
    for (int tt = 0; tt < TILES; tt++) {
        int n = tt * 16 + ln;
        #pragma unroll
        for (int r = 0; r < 4; r++) {
            int m = m0 + wave * 16 + quad * 4 + r;
            if (m < N) {
                if constexpr (F16OUT)
                    feat_out[(size_t)m * CC + n] = (_Float16)acc[tt][r];
                else
                    res_out[(size_t)m * CC + n] = acc[tt][r];
            }
        }
    }
    if constexpr (ATT) {
        #pragma unroll
        for (int hg = 0; hg < H; hg++) {
            float a0 = al[hg * 32 + ln], a1 = al[hg * 32 + 16 + ln];
            float r0 = ar[hg * 32 + ln], r1 = ar[hg * 32 + 16 + ln];
            #pragma unroll
            for (int r = 0; r < 4; r++) {
                float pl = acc[2 * hg][r] * a0 + acc[2 * hg + 1][r] * a1;
                float pr = acc[2 * hg][r] * r0 + acc[2 * hg + 1][r] * r1;
                #pragma unroll
                for (int off = 1; off < 16; off <<= 1) {
                    pl += __shfl_xor(pl, off);
                    pr += __shfl_xor(pr, off);
                }
                int m = m0 + wave * 16 + quad * 4 + r;
                if (ln == 0 && m < N) {
                    el[(size_t)m * H + hg] = pl;
                    er[(size_t)m * H + hg] = pr;
                }
            }
        }
    }
}

// ---------------- single-pass per-node edge softmax + aggregate ----------------

template <int H, bool RELU, bool MEAN>
__global__ void gat_agg(const _Float16* __restrict__ feat, const float* __restrict__ el,
                        const float* __restrict__ er, const int* __restrict__ row_start,
                        const int* __restrict__ csr_src, const float* __restrict__ bias,
                        const float* __restrict__ residual, float* __restrict__ out, int N) {
    constexpr int ROW = H * 32;
    constexpr int CHUNK = 128;
    __shared__ int   s_src[CHUNK];
    __shared__ float s_w[CHUNK][H];
    __shared__ float s_er[H], s_m[H], s_d[H], s_scale[H];
    __shared__ float s_red[MEAN ? ROW : 1];

    int n = blockIdx.x;
    int t = threadIdx.x;       // output dim: h*32 + d
    int h = t >> 5;

    int start = row_start[n];
    int end   = row_start[n + 1];

    if (t < H) {
        s_er[t] = er[(size_t)n * H + t];
        s_m[t]  = -INFINITY;
        s_d[t]  = 0.f;
    }
    __syncthreads();

    float acc = 0.f;
    for (int cs = start; cs < end; cs += CHUNK) {
        int c = end - cs; if (c > CHUNK) c = CHUNK;

        for (int i = t; i < c; i += ROW) s_src[i] = csr_src[cs + i];
        __syncthreads();

        for (int i = t; i < c * H; i += ROW) {
            int j = i / H, hh = i - j * H;
            float e = el[(size_t)s_src[j] * H + hh] + s_er[hh];
            s_w[j][hh] = (e >= 0.f) ? e : 0.2f * e;
        }
        __syncthreads();

        if (t < H) {
            float mold = s_m[t];
            float mnew = mold;
            for (int j = 0; j < c; j++) mnew = fmaxf(mnew, s_w[j][t]);
            float sc = __expf(mold - mnew);
            float d = s_d[t] * sc;
            for (int j = 0; j < c; j++) {
                float w = __expf(s_w[j][t] - mnew);
                s_w[j][t] = w;
                d += w;
            }
            s_m[t] = mnew; s_d[t] = d; s_scale[t] = sc;
        }
        __syncthreads();

        acc *= s_scale[h];

        int j = 0;
        for (; j + 8 <= c; j += 8) {
            float fv[8], wv[8];
            #pragma unroll
            for (int q = 0; q < 8; q++) {
                int s = s_src[j + q];
                fv[q] = (float)feat[(size_t)s * ROW + t];
                wv[q] = s_w[j + q][h];
            }
            #pragma unroll
            for (int q = 0; q < 8; q++) acc += wv[q] * fv[q];
        }
        for (; j < c; j++) acc += s_w[j][h] * (float)feat[(size_t)s_src[j] * ROW + t];
        __syncthreads();
    }

    float rst = acc / fmaxf(s_d[h], 1e-9f);
    rst += bias[t];
    if (residual) rst += residual[(size_t)n * ROW + t];
    if (RELU) rst = fmaxf(rst, 0.f);

    if (!MEAN) {
        out[(size_t)n * ROW + t] = rst;
    } else {
        s_red[t] = rst;
        __syncthreads();
        if (t < 32) {
            float v = 0.f;
            #pragma unroll
            for (int hh = 0; hh < H; hh++) v += s_red[hh * 32 + t];
            out[(size_t)n * 32 + t] = v * (1.0f / H);
        }
    }
}

// ---------------- launch ----------------

extern "C" void kernel_launch(void* const* d_in, const int* in_sizes, int n_in,
                              void* d_out, int out_size, void* d_ws, size_t ws_size,
                              hipStream_t stream) {
    const float* x    = (const float*)d_in[0];
    const int*   src  = (const int*)d_in[1];
    const int*   dst  = (const int*)d_in[2];
    const float* W1   = (const float*)d_in[3];
    const float* al1  = (const float*)d_in[4];
    const float* ar1  = (const float*)d_in[5];
    const float* b1   = (const float*)d_in[6];
    const float* W2   = (const float*)d_in[7];
    const float* al2  = (const float*)d_in[8];
    const float* ar2  = (const float*)d_in[9];
    const float* b2   = (const float*)d_in[10];
    const float* W3   = (const float*)d_in[11];
    const float* al3  = (const float*)d_in[12];
    const float* ar3  = (const float*)d_in[13];
    const float* b3   = (const float*)d_in[14];
    const float* resW3= (const float*)d_in[15];
    float* out = (float*)d_out;

    const int N = in_sizes[0] / 128;
    const int E = in_sizes[1];

    // workspace layout
    float* fws  = (float*)d_ws;
    float* h1v  = fws;                          // N*128
    float* h2v  = h1v + (size_t)N * 128;        // N*128
    float* res3 = h2v + (size_t)N * 128;        // N*192
    float* elb  = res3 + (size_t)N * 192;       // N*6
    float* erb  = elb + (size_t)N * 6;          // N*6
    _Float16* feat_h = (_Float16*)(erb + (size_t)N * 6);  // N*192 f16
    _Float16* wts = feat_h + (size_t)N * 192;   // 163840 f16
    int* deg       = (int*)(wts + 163840);         // N
    int* row_start = deg + N;                      // N+1
    int* csr_src   = row_start + (N + 1);          // E

    const _Float16* W1h = wts;
    const _Float16* W1l = wts + 16384;
    const _Float16* W2h = wts + 32768;
    const _Float16* W2l = wts + 49152;
    const _Float16* W3h = wts + 65536;            // cols 0..191 of L3 block
    const _Float16* W3l = wts + 65536 + 49152;
    const _Float16* Wrh = W3h + 192 * 128;        // cols 192..383 (resW3)
    const _Float16* Wrl = W3l + 192 * 128;

    // ---- CSR build (by dst) + weight split ----
    hipMemsetAsync(deg, 0, (size_t)N * sizeof(int), stream);
    hist_kernel<<<dim3((E + 255) / 256), dim3(256), 0, stream>>>(dst, E, deg);
    scan_kernel<<<dim3(1), dim3(1024), 0, stream>>>(deg, row_start, N);
    hipMemsetAsync(deg, 0, (size_t)N * sizeof(int), stream);
    fill_kernel<<<dim3((E + 255) / 256), dim3(256), 0, stream>>>(src, dst, E, row_start, deg, csr_src);
    wsplit_all<<<dim3(320), dim3(256), 0, stream>>>(W1, W2, W3, resW3, wts);

    dim3 mb((N + 63) / 64);

    // ---- Layer 1 ----
    mfma_fc<128, 4, true, true><<<mb, dim3(256), 0, stream>>>(
        x, W1h, W1l, al1, ar1, feat_h, nullptr, elb, erb, N);
    gat_agg<4, true, false><<<dim3(N), dim3(128), 0, stream>>>(
        feat_h, elb, erb, row_start, csr_src, b1, nullptr, h1v, N);

    // ---- Layer 2 ----
    mfma_fc<128, 4, true, true><<<mb, dim3(256), 0, stream>>>(
        h1v, W2h, W2l, al2, ar2, feat_h, nullptr, elb, erb, N);
    gat_agg<4, true, false><<<dim3(N), dim3(128), 0, stream>>>(
        feat_h, elb, erb, row_start, csr_src, b2, h1v, h2v, N);

    // ---- Layer 3: two CC=192 GEMMs (feat f16 + projected residual fp32) ----
    mfma_fc<192, 6, true, true><<<mb, dim3(256), 0, stream>>>(
        h2v, W3h, W3l, al3, ar3, feat_h, nullptr, elb, erb, N);
    mfma_fc<192, 1, false, false><<<mb, dim3(256), 0, stream>>>(
        h2v, Wrh, Wrl, nullptr, nullptr, nullptr, res3, nullptr, nullptr, N);
    gat_agg<6, false, true><<<dim3(N), dim3(192), 0, stream>>>(
        feat_h, elb, erb, row_start, csr_src, b3, res3, out, N);
}

// Round 6
// 709.875 us; speedup vs baseline: 1.1777x; 1.0240x over previous
//
#include <hip/hip_runtime.h>
#include <math.h>

// GAT 3-layer forward on MI355X.
// N=50000 nodes, E=850000 edges (incl self loops), IN=128, HID=OUT=32, HEADS=(4,4,6).
// GEMMs: split-f16 MFMA (hi/lo, 3 mfma), fully unrolled tile loop (NEVER partial-unroll
// the tt loop: dynamic acc[] indexing -> scratch spill, 445MB spill traffic in round 4).
// Aggregation: one block/node, dim-pair threads (4B f16x2 gathers), parallel per-head
// softmax (32 lanes/head butterfly), online rescale across 128-edge chunks.

typedef _Float16 v8h __attribute__((ext_vector_type(8)));
typedef _Float16 h2v __attribute__((ext_vector_type(2)));
typedef float f32x4 __attribute__((ext_vector_type(4)));

// ---------------- CSR build (by dst) ----------------

__global__ void hist_kernel(const int* __restrict__ dst, int E, int* __restrict__ deg) {
    int i = blockIdx.x * blockDim.x + threadIdx.x;
    if (i < E) atomicAdd(&deg[dst[i]], 1);
}

__global__ void scan_kernel(const int* __restrict__ deg, int* __restrict__ row_start, int n) {
    const int T = 1024;
    __shared__ int sums[T];
    int t = threadIdx.x;
    int chunk = (n + T - 1) / T;
    int begin = t * chunk;
    int finish = begin + chunk; if (finish > n) finish = n;
    int s = 0;
    for (int i = begin; i < finish; i++) s += deg[i];
    sums[t] = s;
    __syncthreads();
    for (int off = 1; off < T; off <<= 1) {
        int u = (t >= off) ? sums[t - off] : 0;
        __syncthreads();
        sums[t] += u;
        __syncthreads();
    }
    int base = (t == 0) ? 0 : sums[t - 1];
    for (int i = begin; i < finish; i++) { row_start[i] = base; base += deg[i]; }
    if (t == T - 1) row_start[n] = sums[T - 1];
}

__global__ void fill_kernel(const int* __restrict__ src, const int* __restrict__ dst, int E,
                            const int* __restrict__ row_start, int* __restrict__ cursor,
                            int* __restrict__ csr_src) {
    int i = blockIdx.x * blockDim.x + threadIdx.x;
    if (i < E) {
        int d = dst[i];
        int pos = atomicAdd(&cursor[d], 1);
        csr_src[row_start[d] + pos] = src[i];
    }
}

// ---------------- weight transpose + f16 hi/lo split (once per call) ----------------
// n-major [c][128] f16. W1h@0 W1l@16384 W2h@32768 W2l@49152
// L3 combined (cols 0..191 = W3, 192..383 = resW3): hi@65536, lo@114688.

__global__ void wsplit_all(const float* __restrict__ W1, const float* __restrict__ W2,
                           const float* __restrict__ W3, const float* __restrict__ Wr,
                           _Float16* __restrict__ o) {
    int i = blockIdx.x * blockDim.x + threadIdx.x;
    if (i >= 81920) return;
    float v; int ohi, e, stride;
    if (i < 16384) {
        e = i; int c = e >> 7, k = e & 127;
        v = W1[(size_t)k * 128 + c]; ohi = 0; stride = 16384;
    } else if (i < 32768) {
        e = i - 16384; int c = e >> 7, k = e & 127;
        v = W2[(size_t)k * 128 + c]; ohi = 32768; stride = 16384;
    } else {
        e = i - 32768; int c = e >> 7, k = e & 127;
        v = (c < 192) ? W3[(size_t)k * 192 + c] : Wr[(size_t)k * 192 + (c - 192)];
        ohi = 65536; stride = 49152;
    }
    _Float16 hv = (_Float16)v;
    o[ohi + e] = hv;
    o[ohi + stride + e] = (_Float16)(v - (float)hv);
}

// ---------------- A staging helper: fp32 -> hi/lo f16 in padded LDS ----------------

template <int AST>
__device__ inline void stage_A(const float* __restrict__ hsrc, _Float16* a_hi, _Float16* a_lo,
                               int m0, int t, int N) {
    for (int i = t; i < 64 * 32; i += 256) {
        int r = i >> 5;
        int c4 = (i & 31) << 2;
        float4 v = make_float4(0.f, 0.f, 0.f, 0.f);
        int m = m0 + r;
        if (m < N) v = *(const float4*)(hsrc + (size_t)m * 128 + c4);
        _Float16* ph = a_hi + r * AST + c4;
        _Float16* pl = a_lo + r * AST + c4;
        float vv[4] = {v.x, v.y, v.z, v.w};
        #pragma unroll
        for (int q = 0; q < 4; q++) {
            _Float16 hh = (_Float16)vv[q];
            ph[q] = hh;
            pl[q] = (_Float16)(vv[q] - (float)hh);
        }
    }
}

// ---------------- MFMA fc (+ attention logits), layers 1/2 ----------------

template <int CC, int H>
__global__ __launch_bounds__(256) void mfma_fc(
    const float* __restrict__ hsrc,
    const _Float16* __restrict__ Bhi, const _Float16* __restrict__ Blo,
    const float* __restrict__ al, const float* __restrict__ ar,
    _Float16* __restrict__ feat_out,
    float* __restrict__ el, float* __restrict__ er, int N) {
    constexpr int TILES = CC / 16;
    constexpr int AST = 128 + 8;
    __shared__ _Float16 a_hi[64 * AST];
    __shared__ _Float16 a_lo[64 * AST];

    int m0 = blockIdx.x * 64;
    int t = threadIdx.x;
    stage_A<AST>(hsrc, a_hi, a_lo, m0, t, N);
    __syncthreads();

    int wave = t >> 6, lane = t & 63, ln = lane & 15, quad = lane >> 4;

    f32x4 acc[TILES];
    #pragma unroll
    for (int i = 0; i < TILES; i++) acc[i] = (f32x4){0.f, 0.f, 0.f, 0.f};

    const _Float16* arow_h = a_hi + (wave * 16 + ln) * AST;
    const _Float16* arow_l = a_lo + (wave * 16 + ln) * AST;

    #pragma unroll
    for (int k0 = 0; k0 < 128; k0 += 32) {
        v8h ah = *(const v8h*)(arow_h + k0 + quad * 8);
        v8h alo = *(const v8h*)(arow_l + k0 + quad * 8);
        #pragma unroll
        for (int tt = 0; tt < TILES; tt++) {
            size_t boff = (size_t)(tt * 16 + ln) * 128 + k0 + quad * 8;
            v8h bh = *(const v8h*)(Bhi + boff);
            v8h bl = *(const v8h*)(Blo + boff);
            acc[tt] = __builtin_amdgcn_mfma_f32_16x16x32_f16(alo, bh, acc[tt], 0, 0, 0);
            acc[tt] = __builtin_amdgcn_mfma_f32_16x16x32_f16(ah, bl, acc[tt], 0, 0, 0);
            acc[tt] = __builtin_amdgcn_mfma_f32_16x16x32_f16(ah, bh, acc[tt], 0, 0, 0);
        }
    }

    #pragma unroll
    for (int tt = 0; tt < TILES; tt++) {
        int n = tt * 16 + ln;
        #pragma unroll
        for (int r = 0; r < 4; r++) {
            int m = m0 + wave * 16 + quad * 4 + r;
            if (m < N) feat_out[(size_t)m * CC + n] = (_Float16)acc[tt][r];
        }
    }
    #pragma unroll
    for (int hg = 0; hg < H; hg++) {
        float a0 = al[hg * 32 + ln], a1 = al[hg * 32 + 16 + ln];
        float r0 = ar[hg * 32 + ln], r1 = ar[hg * 32 + 16 + ln];
        #pragma unroll
        for (int r = 0; r < 4; r++) {
            float pl = acc[2 * hg][r] * a0 + acc[2 * hg + 1][r] * a1;
            float pr = acc[2 * hg][r] * r0 + acc[2 * hg + 1][r] * r1;
            #pragma unroll
            for (int off = 1; off < 16; off <<= 1) {
                pl += __shfl_xor(pl, off);
                pr += __shfl_xor(pr, off);
            }
            int m = m0 + wave * 16 + quad * 4 + r;
            if (ln == 0 && m < N) {
                el[(size_t)m * H + hg] = pl;
                er[(size_t)m * H + hg] = pr;
            }
        }
    }
}

// ---------------- MFMA fc layer 3: dual grid (y=0: W3+att f16; y=1: resW3 fp32) ----------------

__global__ __launch_bounds__(256) void mfma_fc3(
    const float* __restrict__ hsrc,
    const _Float16* __restrict__ B3h, const _Float16* __restrict__ B3l,
    const _Float16* __restrict__ Brh, const _Float16* __restrict__ Brl,
    const float* __restrict__ al, const float* __restrict__ ar,
    _Float16* __restrict__ feat_out, float* __restrict__ res_out,
    float* __restrict__ el, float* __restrict__ er, int N) {
    constexpr int CC = 192, H = 6, TILES = 12;
    constexpr int AST = 128 + 8;
    __shared__ _Float16 a_hi[64 * AST];
    __shared__ _Float16 a_lo[64 * AST];

    const bool isres = (blockIdx.y == 1);
    const _Float16* __restrict__ Bhi = isres ? Brh : B3h;
    const _Float16* __restrict__ Blo = isres ? Brl : B3l;

    int m0 = blockIdx.x * 64;
    int t = threadIdx.x;
    stage_A<AST>(hsrc, a_hi, a_lo, m0, t, N);
    __syncthreads();

    int wave = t >> 6, lane = t & 63, ln = lane & 15, quad = lane >> 4;

    f32x4 acc[TILES];
    #pragma unroll
    for (int i = 0; i < TILES; i++) acc[i] = (f32x4){0.f, 0.f, 0.f, 0.f};

    const _Float16* arow_h = a_hi + (wave * 16 + ln) * AST;
    const _Float16* arow_l = a_lo + (wave * 16 + ln) * AST;

    #pragma unroll
    for (int k0 = 0; k0 < 128; k0 += 32) {
        v8h ah = *(const v8h*)(arow_h + k0 + quad * 8);
        v8h alo = *(const v8h*)(arow_l + k0 + quad * 8);
        #pragma unroll
        for (int tt = 0; tt < TILES; tt++) {
            size_t boff = (size_t)(tt * 16 + ln) * 128 + k0 + quad * 8;
            v8h bh = *(const v8h*)(Bhi + boff);
            v8h bl = *(const v8h*)(Blo + boff);
            acc[tt] = __builtin_amdgcn_mfma_f32_16x16x32_f16(alo, bh, acc[tt], 0, 0, 0);
            acc[tt] = __builtin_amdgcn_mfma_f32_16x16x32_f16(ah, bl, acc[tt], 0, 0, 0);
            acc[tt] = __builtin_amdgcn_mfma_f32_16x16x32_f16(ah, bh, acc[tt], 0, 0, 0);
        }
    }

    if (!isres) {
        #pragma unroll
        for (int tt = 0; tt < TILES; tt++) {
            int n = tt * 16 + ln;
            #pragma unroll
            for (int r = 0; r < 4; r++) {
                int m = m0 + wave * 16 + quad * 4 + r;
                if (m < N) feat_out[(size_t)m * CC + n] = (_Float16)acc[tt][r];
            }
        }
        #pragma unroll
        for (int hg = 0; hg < H; hg++) {
            float a0 = al[hg * 32 + ln], a1 = al[hg * 32 + 16 + ln];
            float r0 = ar[hg * 32 + ln], r1 = ar[hg * 32 + 16 + ln];
            #pragma unroll
            for (int r = 0; r < 4; r++) {
                float pl = acc[2 * hg][r] * a0 + acc[2 * hg + 1][r] * a1;
                float pr = acc[2 * hg][r] * r0 + acc[2 * hg + 1][r] * r1;
                #pragma unroll
                for (int off = 1; off < 16; off <<= 1) {
                    pl += __shfl_xor(pl, off);
                    pr += __shfl_xor(pr, off);
                }
                int m = m0 + wave * 16 + quad * 4 + r;
                if (ln == 0 && m < N) {
                    el[(size_t)m * H + hg] = pl;
                    er[(size_t)m * H + hg] = pr;
                }
            }
        }
    } else {
        #pragma unroll
        for (int tt = 0; tt < TILES; tt++) {
            int n = tt * 16 + ln;
            #pragma unroll
            for (int r = 0; r < 4; r++) {
                int m = m0 + wave * 16 + quad * 4 + r;
                if (m < N) res_out[(size_t)m * CC + n] = acc[tt][r];
            }
        }
    }
}

// ---------------- per-node edge softmax + aggregate ----------------
// NT threads; thread = (edge-group g, dim-pair d2). f16x2 gathers (4B/lane),
// parallel per-head softmax (32 lanes/head), online rescale across chunks.

template <int H, bool RELU, bool MEAN, int NT>
__global__ __launch_bounds__(NT) void gat_agg(
        const _Float16* __restrict__ feat, const float* __restrict__ el,
        const float* __restrict__ er, const int* __restrict__ row_start,
        const int* __restrict__ csr_src, const float* __restrict__ bias,
        const float* __restrict__ residual, float* __restrict__ out, int N) {
    constexpr int ROW = H * 32;
    constexpr int HW = ROW / 2;      // threads per edge group (dim pairs)
    constexpr int G = NT / HW;       // edge groups
    constexpr int CHUNK = 128;
    static_assert(NT % HW == 0 && NT >= H * 32, "layout");

    __shared__ int   s_src[CHUNK];
    __shared__ float s_w[CHUNK][H];
    __shared__ float s_er[H], s_m[H], s_d[H], s_scale[H];
    __shared__ float s_part[G][ROW];
    __shared__ float s_red[MEAN ? ROW : 1];

    int n = blockIdx.x;
    int t = threadIdx.x;
    int d2 = t % HW;        // dim pair: dims 2*d2, 2*d2+1
    int g  = t / HW;        // edge group
    int hd = d2 >> 4;       // head of this dim pair

    int start = row_start[n];
    int end   = row_start[n + 1];

    if (t < H) {
        s_er[t] = er[(size_t)n * H + t];
        s_m[t]  = -INFINITY;
        s_d[t]  = 0.f;
    }
    __syncthreads();

    float acc0 = 0.f, acc1 = 0.f;
    for (int cs = start; cs < end; cs += CHUNK) {
        int c = end - cs; if (c > CHUNK) c = CHUNK;

        for (int i = t; i < c; i += NT) s_src[i] = csr_src[cs + i];
        __syncthreads();

        // logits (coalesced el gathers; el table is L2-resident)
        for (int i = t; i < c * H; i += NT) {
            int j = i / H, hh = i - j * H;
            float e = el[(size_t)s_src[j] * H + hh] + s_er[hh];
            s_w[j][hh] = (e >= 0.f) ? e : 0.2f * e;
        }
        __syncthreads();

        // parallel per-head online max + denom: 32 lanes per head
        if (t < H * 32) {
            int hh = t >> 5, ll = t & 31;
            float mloc = -INFINITY;
            for (int j = ll; j < c; j += 32) mloc = fmaxf(mloc, s_w[j][hh]);
            #pragma unroll
            for (int off = 16; off >= 1; off >>= 1) mloc = fmaxf(mloc, __shfl_xor(mloc, off));
            float mold = s_m[hh];
            float mnew = fmaxf(mold, mloc);
            float dloc = 0.f;
            for (int j = ll; j < c; j += 32) {
                float w = __expf(s_w[j][hh] - mnew);
                s_w[j][hh] = w;
                dloc += w;
            }
            #pragma unroll
            for (int off = 16; off >= 1; off >>= 1) dloc += __shfl_xor(dloc, off);
            if (ll == 0) {
                float sc = __expf(mold - mnew);
                s_scale[hh] = sc;
                s_d[hh] = s_d[hh] * sc + dloc;
                s_m[hh] = mnew;
            }
        }
        __syncthreads();

        float sc = s_scale[hd];
        acc0 *= sc; acc1 *= sc;

        int j = g;
        for (; j + 3 * G < c; j += 4 * G) {
            int s0 = s_src[j], s1 = s_src[j + G], s2 = s_src[j + 2 * G], s3 = s_src[j + 3 * G];
            float w0 = s_w[j][hd], w1 = s_w[j + G][hd], w2 = s_w[j + 2 * G][hd], w3 = s_w[j + 3 * G][hd];
            h2v v0 = *(const h2v*)(feat + (size_t)s0 * ROW + 2 * d2);
            h2v v1 = *(const h2v*)(feat + (size_t)s1 * ROW + 2 * d2);
            h2v v2 = *(const h2v*)(feat + (size_t)s2 * ROW + 2 * d2);
            h2v v3 = *(const h2v*)(feat + (size_t)s3 * ROW + 2 * d2);
            acc0 += w0 * (float)v0.x + w1 * (float)v1.x + w2 * (float)v2.x + w3 * (float)v3.x;
            acc1 += w0 * (float)v0.y + w1 * (float)v1.y + w2 * (float)v2.y + w3 * (float)v3.y;
        }
        for (; j < c; j += G) {
            int s0 = s_src[j];
            float w0 = s_w[j][hd];
            h2v v0 = *(const h2v*)(feat + (size_t)s0 * ROW + 2 * d2);
            acc0 += w0 * (float)v0.x;
            acc1 += w0 * (float)v0.y;
        }
        __syncthreads();   // protect s_src/s_w before next chunk
    }

    // cross-group reduction
    s_part[g][2 * d2]     = acc0;
    s_part[g][2 * d2 + 1] = acc1;
    __syncthreads();

    float rst = 0.f;
    if (t < ROW) {
        float sum = 0.f;
        #pragma unroll
        for (int gg = 0; gg < G; gg++) sum += s_part[gg][t];
        int h = t >> 5;
        rst = sum / fmaxf(s_d[h], 1e-9f);
        rst += bias[t];
        if (residual) rst += residual[(size_t)n * ROW + t];
        if (RELU) rst = fmaxf(rst, 0.f);
        if (!MEAN) out[(size_t)n * ROW + t] = rst;
    }
    if constexpr (MEAN) {
        if (t < ROW) s_red[t] = rst;
        __syncthreads();
        if (t < 32) {
            float v = 0.f;
            #pragma unroll
            for (int hh = 0; hh < H; hh++) v += s_red[hh * 32 + t];
            out[(size_t)n * 32 + t] = v * (1.0f / H);
        }
    }
}

// ---------------- launch ----------------

extern "C" void kernel_launch(void* const* d_in, const int* in_sizes, int n_in,
                              void* d_out, int out_size, void* d_ws, size_t ws_size,
                              hipStream_t stream) {
    const float* x    = (const float*)d_in[0];
    const int*   src  = (const int*)d_in[1];
    const int*   dst  = (const int*)d_in[2];
    const float* W1   = (const float*)d_in[3];
    const float* al1  = (const float*)d_in[4];
    const float* ar1  = (const float*)d_in[5];
    const float* b1   = (const float*)d_in[6];
    const float* W2   = (const float*)d_in[7];
    const float* al2  = (const float*)d_in[8];
    const float* ar2  = (const float*)d_in[9];
    const float* b2   = (const float*)d_in[10];
    const float* W3   = (const float*)d_in[11];
    const float* al3  = (const float*)d_in[12];
    const float* ar3  = (const float*)d_in[13];
    const float* b3   = (const float*)d_in[14];
    const float* resW3= (const float*)d_in[15];
    float* out = (float*)d_out;

    const int N = in_sizes[0] / 128;
    const int E = in_sizes[1];

    // workspace layout
    float* fws  = (float*)d_ws;
    float* h1v  = fws;                          // N*128
    float* h2v  = h1v + (size_t)N * 128;        // N*128
    float* res3 = h2v + (size_t)N * 128;        // N*192
    float* elb  = res3 + (size_t)N * 192;       // N*6
    float* erb  = elb + (size_t)N * 6;          // N*6
    _Float16* feat_h = (_Float16*)(erb + (size_t)N * 6);  // N*192 f16
    _Float16* wts = feat_h + (size_t)N * 192;   // 163840 f16
    int* deg       = (int*)(wts + 163840);         // N
    int* row_start = deg + N;                      // N+1
    int* csr_src   = row_start + (N + 1);          // E

    const _Float16* W1h = wts;
    const _Float16* W1l = wts + 16384;
    const _Float16* W2h = wts + 32768;
    const _Float16* W2l = wts + 49152;
    const _Float16* W3h = wts + 65536;            // cols 0..191 of L3 block
    const _Float16* W3l = wts + 65536 + 49152;
    const _Float16* Wrh = W3h + 192 * 128;        // cols 192..383 (resW3)
    const _Float16* Wrl = W3l + 192 * 128;

    // ---- CSR build (by dst) + weight split ----
    hipMemsetAsync(deg, 0, (size_t)N * sizeof(int), stream);
    hist_kernel<<<dim3((E + 255) / 256), dim3(256), 0, stream>>>(dst, E, deg);
    scan_kernel<<<dim3(1), dim3(1024), 0, stream>>>(deg, row_start, N);
    hipMemsetAsync(deg, 0, (size_t)N * sizeof(int), stream);
    fill_kernel<<<dim3((E + 255) / 256), dim3(256), 0, stream>>>(src, dst, E, row_start, deg, csr_src);
    wsplit_all<<<dim3(320), dim3(256), 0, stream>>>(W1, W2, W3, resW3, wts);

    dim3 mb((N + 63) / 64);

    // ---- Layer 1 ----
    mfma_fc<128, 4><<<mb, dim3(256), 0, stream>>>(
        x, W1h, W1l, al1, ar1, feat_h, elb, erb, N);
    gat_agg<4, true, false, 256><<<dim3(N), dim3(256), 0, stream>>>(
        feat_h, elb, erb, row_start, csr_src, b1, nullptr, h1v, N);

    // ---- Layer 2 ----
    mfma_fc<128, 4><<<mb, dim3(256), 0, stream>>>(
        h1v, W2h, W2l, al2, ar2, feat_h, elb, erb, N);
    gat_agg<4, true, false, 256><<<dim3(N), dim3(256), 0, stream>>>(
        feat_h, elb, erb, row_start, csr_src, b2, h1v, h2v, N);

    // ---- Layer 3: dual GEMM (y=0: W3 feat f16 + logits; y=1: resW3 fp32) ----
    mfma_fc3<<<dim3(mb.x, 2), dim3(256), 0, stream>>>(
        h2v, W3h, W3l, Wrh, Wrl, al3, ar3, feat_h, res3, elb, erb, N);
    gat_agg<6, false, true, 192><<<dim3(N), dim3(192), 0, stream>>>(
        feat_h, elb, erb, row_start, csr_src, b3, res3, out, N);
}

// Round 7
// 709.707 us; speedup vs baseline: 1.1779x; 1.0002x over previous
//
#include <hip/hip_runtime.h>
#include <math.h>

// GAT 3-layer forward on MI355X.
// N=50000 nodes, E=850000 edges (incl self loops), IN=128, HID=OUT=32, HEADS=(4,4,6).
// GEMMs: split-f16 MFMA (hi/lo, 3 mfma), LDS-free/barrier-free: A is pre-packed in
// MFMA-fragment order (hi/lo f16 planes) by the producer (splitx or agg epilogue), so
// each wave streams A with coalesced dwordx4 loads and B from L2-hot pre-split weights.
// NEVER partial-unroll the tile loop (dynamic acc[] indexing -> scratch spill, round 4).
// Aggregation: one block/node, dim-pair threads (4B f16x2 gathers), parallel per-head
// softmax (32 lanes/head butterfly), online rescale across 128-edge chunks.

typedef _Float16 v8h __attribute__((ext_vector_type(8)));
typedef _Float16 f16x2 __attribute__((ext_vector_type(2)));
typedef float f32x4 __attribute__((ext_vector_type(4)));

// packed A-fragment offset for node/row n, k-dim k (128-wide rows):
// tile(n/16)*2048 + (k/32)*512 + ((k/8)%4)*128 + (n%16)*8 + k%8
__device__ __host__ inline int pack_off(int n, int k) {
    return ((n >> 4) << 11) | ((k >> 5) << 9) | (((k >> 3) & 3) << 7) | ((n & 15) << 3) | (k & 7);
}

// ---------------- CSR build (by dst) ----------------

__global__ void hist_kernel(const int* __restrict__ dst, int E, int* __restrict__ deg) {
    int i = blockIdx.x * blockDim.x + threadIdx.x;
    if (i < E) atomicAdd(&deg[dst[i]], 1);
}

__global__ void scan_kernel(const int* __restrict__ deg, int* __restrict__ row_start, int n) {
    const int T = 1024;
    __shared__ int sums[T];
    int t = threadIdx.x;
    int chunk = (n + T - 1) / T;
    int begin = t * chunk;
    int finish = begin + chunk; if (finish > n) finish = n;
    int s = 0;
    for (int i = begin; i < finish; i++) s += deg[i];
    sums[t] = s;
    __syncthreads();
    for (int off = 1; off < T; off <<= 1) {
        int u = (t >= off) ? sums[t - off] : 0;
        __syncthreads();
        sums[t] += u;
        __syncthreads();
    }
    int base = (t == 0) ? 0 : sums[t - 1];
    for (int i = begin; i < finish; i++) { row_start[i] = base; base += deg[i]; }
    if (t == T - 1) row_start[n] = sums[T - 1];
}

__global__ void fill_kernel(const int* __restrict__ src, const int* __restrict__ dst, int E,
                            const int* __restrict__ row_start, int* __restrict__ cursor,
                            int* __restrict__ csr_src) {
    int i = blockIdx.x * blockDim.x + threadIdx.x;
    if (i < E) {
        int d = dst[i];
        int pos = atomicAdd(&cursor[d], 1);
        csr_src[row_start[d] + pos] = src[i];
    }
}

// ---------------- weight transpose + f16 hi/lo split (once per call) ----------------
// n-major [c][128] f16. W1h@0 W1l@16384 W2h@32768 W2l@49152
// L3 combined (cols 0..191 = W3, 192..383 = resW3): hi@65536, lo@114688.

__global__ void wsplit_all(const float* __restrict__ W1, const float* __restrict__ W2,
                           const float* __restrict__ W3, const float* __restrict__ Wr,
                           _Float16* __restrict__ o) {
    int i = blockIdx.x * blockDim.x + threadIdx.x;
    if (i >= 81920) return;
    float v; int ohi, e, stride;
    if (i < 16384) {
        e = i; int c = e >> 7, k = e & 127;
        v = W1[(size_t)k * 128 + c]; ohi = 0; stride = 16384;
    } else if (i < 32768) {
        e = i - 16384; int c = e >> 7, k = e & 127;
        v = W2[(size_t)k * 128 + c]; ohi = 32768; stride = 16384;
    } else {
        e = i - 32768; int c = e >> 7, k = e & 127;
        v = (c < 192) ? W3[(size_t)k * 192 + c] : Wr[(size_t)k * 192 + (c - 192)];
        ohi = 65536; stride = 49152;
    }
    _Float16 hv = (_Float16)v;
    o[ohi + e] = hv;
    o[ohi + stride + e] = (_Float16)(v - (float)hv);
}

// ---------------- x -> packed hi/lo f16 fragment layout ----------------

__global__ void splitx_kernel(const float* __restrict__ x, _Float16* __restrict__ hi,
                              _Float16* __restrict__ lo, int N, int PT) {
    int i = blockIdx.x * blockDim.x + threadIdx.x;
    if (i >= PT * 2048) return;
    int mt = i >> 11, r = i & 2047;
    int q4 = r >> 9, quad = (r >> 7) & 3, ln = (r >> 3) & 15, j = r & 7;
    int n = mt * 16 + ln, k = q4 * 32 + quad * 8 + j;
    float v = (n < N) ? x[(size_t)n * 128 + k] : 0.f;
    _Float16 h = (_Float16)v;
    hi[i] = h;
    lo[i] = (_Float16)(v - (float)h);
}

// ---------------- LDS-free MFMA fc (+ attention logits), layers 1/2 ----------------
// 4 waves/block, wave handles 16 rows (one packed tile) x all CC cols.

template <int CC, int H>
__global__ __launch_bounds__(256, 4) void mfma_fc(
    const _Float16* __restrict__ Ahi, const _Float16* __restrict__ Alo,
    const _Float16* __restrict__ Bhi, const _Float16* __restrict__ Blo,
    const float* __restrict__ al, const float* __restrict__ ar,
    _Float16* __restrict__ feat_out,
    float* __restrict__ el, float* __restrict__ er, int N) {
    constexpr int TILES = CC / 16;
    int t = threadIdx.x;
    int wave = t >> 6, lane = t & 63;
    int ln = lane & 15, quad = lane >> 4;
    int mt = blockIdx.x * 4 + wave;

    f32x4 acc[TILES];
    #pragma unroll
    for (int i = 0; i < TILES; i++) acc[i] = (f32x4){0.f, 0.f, 0.f, 0.f};

    const _Float16* pa_h = Ahi + (size_t)mt * 2048 + quad * 128 + ln * 8;
    const _Float16* pa_l = Alo + (size_t)mt * 2048 + quad * 128 + ln * 8;

    #pragma unroll
    for (int q4 = 0; q4 < 4; q4++) {
        v8h ah = *(const v8h*)(pa_h + q4 * 512);
        v8h av = *(const v8h*)(pa_l + q4 * 512);
        #pragma unroll
        for (int tt = 0; tt < TILES; tt++) {
            size_t boff = (size_t)(tt * 16 + ln) * 128 + q4 * 32 + quad * 8;
            v8h bh = *(const v8h*)(Bhi + boff);
            v8h bl = *(const v8h*)(Blo + boff);
            acc[tt] = __builtin_amdgcn_mfma_f32_16x16x32_f16(av, bh, acc[tt], 0, 0, 0);
            acc[tt] = __builtin_amdgcn_mfma_f32_16x16x32_f16(ah, bl, acc[tt], 0, 0, 0);
            acc[tt] = __builtin_amdgcn_mfma_f32_16x16x32_f16(ah, bh, acc[tt], 0, 0, 0);
        }
    }

    // C/D layout: col=lane&15, row=quad*4+reg
    #pragma unroll
    for (int tt = 0; tt < TILES; tt++) {
        int n = tt * 16 + ln;
        #pragma unroll
        for (int r = 0; r < 4; r++) {
            int m = mt * 16 + quad * 4 + r;
            if (m < N) feat_out[(size_t)m * CC + n] = (_Float16)acc[tt][r];
        }
    }
    #pragma unroll
    for (int hg = 0; hg < H; hg++) {
        float a0 = al[hg * 32 + ln], a1 = al[hg * 32 + 16 + ln];
        float r0 = ar[hg * 32 + ln], r1 = ar[hg * 32 + 16 + ln];
        #pragma unroll
        for (int r = 0; r < 4; r++) {
            float pl = acc[2 * hg][r] * a0 + acc[2 * hg + 1][r] * a1;
            float pr = acc[2 * hg][r] * r0 + acc[2 * hg + 1][r] * r1;
            #pragma unroll
            for (int off = 1; off < 16; off <<= 1) {
                pl += __shfl_xor(pl, off);
                pr += __shfl_xor(pr, off);
            }
            int m = mt * 16 + quad * 4 + r;
            if (ln == 0 && m < N) {
                el[(size_t)m * H + hg] = pl;
                er[(size_t)m * H + hg] = pr;
            }
        }
    }
}

// ---------------- layer 3: dual grid (y=0: W3 feat f16 + logits; y=1: resW3 fp32) ----------------

__global__ __launch_bounds__(256, 3) void mfma_fc3(
    const _Float16* __restrict__ Ahi, const _Float16* __restrict__ Alo,
    const _Float16* __restrict__ B3h, const _Float16* __restrict__ B3l,
    const _Float16* __restrict__ Brh, const _Float16* __restrict__ Brl,
    const float* __restrict__ al, const float* __restrict__ ar,
    _Float16* __restrict__ feat_out, float* __restrict__ res_out,
    float* __restrict__ el, float* __restrict__ er, int N) {
    constexpr int CC = 192, H = 6, TILES = 12;
    const bool isres = (blockIdx.y == 1);
    const _Float16* __restrict__ Bhi = isres ? Brh : B3h;
    const _Float16* __restrict__ Blo = isres ? Brl : B3l;

    int t = threadIdx.x;
    int wave = t >> 6, lane = t & 63;
    int ln = lane & 15, quad = lane >> 4;
    int mt = blockIdx.x * 4 + wave;

    f32x4 acc[TILES];
    #pragma unroll
    for (int i = 0; i < TILES; i++) acc[i] = (f32x4){0.f, 0.f, 0.f, 0.f};

    const _Float16* pa_h = Ahi + (size_t)mt * 2048 + quad * 128 + ln * 8;
    const _Float16* pa_l = Alo + (size_t)mt * 2048 + quad * 128 + ln * 8;

    #pragma unroll
    for (int q4 = 0; q4 < 4; q4++) {
        v8h ah = *(const v8h*)(pa_h + q4 * 512);
        v8h av = *(const v8h*)(pa_l + q4 * 512);
        #pragma unroll
        for (int tt = 0; tt < TILES; tt++) {
            size_t boff = (size_t)(tt * 16 + ln) * 128 + q4 * 32 + quad * 8;
            v8h bh = *(const v8h*)(Bhi + boff);
            v8h bl = *(const v8h*)(Blo + boff);
            acc[tt] = __builtin_amdgcn_mfma_f32_16x16x32_f16(av, bh, acc[tt], 0, 0, 0);
            acc[tt] = __builtin_amdgcn_mfma_f32_16x16x32_f16(ah, bl, acc[tt], 0, 0, 0);
            acc[tt] = __builtin_amdgcn_mfma_f32_16x16x32_f16(ah, bh, acc[tt], 0, 0, 0);
        }
    }

    if (!isres) {
        #pragma unroll
        for (int tt = 0; tt < TILES; tt++) {
            int n = tt * 16 + ln;
            #pragma unroll
            for (int r = 0; r < 4; r++) {
                int m = mt * 16 + quad * 4 + r;
                if (m < N) feat_out[(size_t)m * CC + n] = (_Float16)acc[tt][r];
            }
        }
        #pragma unroll
        for (int hg = 0; hg < H; hg++) {
            float a0 = al[hg * 32 + ln], a1 = al[hg * 32 + 16 + ln];
            float r0 = ar[hg * 32 + ln], r1 = ar[hg * 32 + 16 + ln];
            #pragma unroll
            for (int r = 0; r < 4; r++) {
                float pl = acc[2 * hg][r] * a0 + acc[2 * hg + 1][r] * a1;
                float pr = acc[2 * hg][r] * r0 + acc[2 * hg + 1][r] * r1;
                #pragma unroll
                for (int off = 1; off < 16; off <<= 1) {
                    pl += __shfl_xor(pl, off);
                    pr += __shfl_xor(pr, off);
                }
                int m = mt * 16 + quad * 4 + r;
                if (ln == 0 && m < N) {
                    el[(size_t)m * H + hg] = pl;
                    er[(size_t)m * H + hg] = pr;
                }
            }
        }
    } else {
        #pragma unroll
        for (int tt = 0; tt < TILES; tt++) {
            int n = tt * 16 + ln;
            #pragma unroll
            for (int r = 0; r < 4; r++) {
                int m = mt * 16 + quad * 4 + r;
                if (m < N) res_out[(size_t)m * CC + n] = acc[tt][r];
            }
        }
    }
}

// ---------------- per-node edge softmax + aggregate ----------------
// RES: 0 none, 1 packed hi/lo (identity residual), 2 plain fp32.
// PACK: write result as packed hi/lo f16 planes (next GEMM's A); else plain/mean.

template <int H, bool RELU, bool MEAN, int NT, int RES, bool PACK>
__global__ __launch_bounds__(NT) void gat_agg(
        const _Float16* __restrict__ feat, const float* __restrict__ el,
        const float* __restrict__ er, const int* __restrict__ row_start,
        const int* __restrict__ csr_src, const float* __restrict__ bias,
        const float* __restrict__ res_plain,
        const _Float16* __restrict__ res_hi, const _Float16* __restrict__ res_lo,
        float* __restrict__ out, _Float16* __restrict__ out_hi, _Float16* __restrict__ out_lo,
        int N) {
    constexpr int ROW = H * 32;
    constexpr int HW = ROW / 2;      // threads per edge group (dim pairs)
    constexpr int G = NT / HW;       // edge groups
    constexpr int CHUNK = 128;
    static_assert(NT % HW == 0 && NT >= H * 32, "layout");

    __shared__ int   s_src[CHUNK];
    __shared__ float s_w[CHUNK][H];
    __shared__ float s_er[H], s_m[H], s_d[H], s_scale[H];
    __shared__ float s_part[G][ROW];
    __shared__ float s_red[MEAN ? ROW : 1];

    int n = blockIdx.x;
    int t = threadIdx.x;
    int d2 = t % HW;        // dim pair: dims 2*d2, 2*d2+1
    int g  = t / HW;        // edge group
    int hd = d2 >> 4;       // head of this dim pair

    int start = row_start[n];
    int end   = row_start[n + 1];

    if (t < H) {
        s_er[t] = er[(size_t)n * H + t];
        s_m[t]  = -INFINITY;
        s_d[t]  = 0.f;
    }
    __syncthreads();

    float acc0 = 0.f, acc1 = 0.f;
    for (int cs = start; cs < end; cs += CHUNK) {
        int c = end - cs; if (c > CHUNK) c = CHUNK;

        for (int i = t; i < c; i += NT) s_src[i] = csr_src[cs + i];
        __syncthreads();

        for (int i = t; i < c * H; i += NT) {
            int j = i / H, hh = i - j * H;
            float e = el[(size_t)s_src[j] * H + hh] + s_er[hh];
            s_w[j][hh] = (e >= 0.f) ? e : 0.2f * e;
        }
        __syncthreads();

        // parallel per-head online max + denom: 32 lanes per head
        if (t < H * 32) {
            int hh = t >> 5, ll = t & 31;
            float mloc = -INFINITY;
            for (int j = ll; j < c; j += 32) mloc = fmaxf(mloc, s_w[j][hh]);
            #pragma unroll
            for (int off = 16; off >= 1; off >>= 1) mloc = fmaxf(mloc, __shfl_xor(mloc, off));
            float mold = s_m[hh];
            float mnew = fmaxf(mold, mloc);
            float dloc = 0.f;
            for (int j = ll; j < c; j += 32) {
                float w = __expf(s_w[j][hh] - mnew);
                s_w[j][hh] = w;
                dloc += w;
            }
            #pragma unroll
            for (int off = 16; off >= 1; off >>= 1) dloc += __shfl_xor(dloc, off);
            if (ll == 0) {
                float sc = __expf(mold - mnew);
                s_scale[hh] = sc;
                s_d[hh] = s_d[hh] * sc + dloc;
                s_m[hh] = mnew;
            }
        }
        __syncthreads();

        float sc = s_scale[hd];
        acc0 *= sc; acc1 *= sc;

        int j = g;
        for (; j + 3 * G < c; j += 4 * G) {
            int s0 = s_src[j], s1 = s_src[j + G], s2 = s_src[j + 2 * G], s3 = s_src[j + 3 * G];
            float w0 = s_w[j][hd], w1 = s_w[j + G][hd], w2 = s_w[j + 2 * G][hd], w3 = s_w[j + 3 * G][hd];
            f16x2 v0 = *(const f16x2*)(feat + (size_t)s0 * ROW + 2 * d2);
            f16x2 v1 = *(const f16x2*)(feat + (size_t)s1 * ROW + 2 * d2);
            f16x2 v2 = *(const f16x2*)(feat + (size_t)s2 * ROW + 2 * d2);
            f16x2 v3 = *(const f16x2*)(feat + (size_t)s3 * ROW + 2 * d2);
            acc0 += w0 * (float)v0.x + w1 * (float)v1.x + w2 * (float)v2.x + w3 * (float)v3.x;
            acc1 += w0 * (float)v0.y + w1 * (float)v1.y + w2 * (float)v2.y + w3 * (float)v3.y;
        }
        for (; j < c; j += G) {
            int s0 = s_src[j];
            float w0 = s_w[j][hd];
            f16x2 v0 = *(const f16x2*)(feat + (size_t)s0 * ROW + 2 * d2);
            acc0 += w0 * (float)v0.x;
            acc1 += w0 * (float)v0.y;
        }
        __syncthreads();   // protect s_src/s_w before next chunk
    }

    // cross-group reduction
    s_part[g][2 * d2]     = acc0;
    s_part[g][2 * d2 + 1] = acc1;
    __syncthreads();

    float rst = 0.f;
    if (t < ROW) {
        float sum = 0.f;
        #pragma unroll
        for (int gg = 0; gg < G; gg++) sum += s_part[gg][t];
        int h = t >> 5;
        rst = sum / fmaxf(s_d[h], 1e-9f);
        rst += bias[t];
        if constexpr (RES == 1) {
            int off = pack_off(n, t);
            rst += (float)res_hi[off] + (float)res_lo[off];
        } else if constexpr (RES == 2) {
            rst += res_plain[(size_t)n * ROW + t];
        }
        if (RELU) rst = fmaxf(rst, 0.f);
        if constexpr (PACK) {
            int off = pack_off(n, t);
            _Float16 hh = (_Float16)rst;
            out_hi[off] = hh;
            out_lo[off] = (_Float16)(rst - (float)hh);
        } else if constexpr (!MEAN) {
            out[(size_t)n * ROW + t] = rst;
        }
    }
    if constexpr (MEAN) {
        if (t < ROW) s_red[t] = rst;
        __syncthreads();
        if (t < 32) {
            float v = 0.f;
            #pragma unroll
            for (int hh = 0; hh < H; hh++) v += s_red[hh * 32 + t];
            out[(size_t)n * 32 + t] = v * (1.0f / H);
        }
    }
}

// ---------------- launch ----------------

extern "C" void kernel_launch(void* const* d_in, const int* in_sizes, int n_in,
                              void* d_out, int out_size, void* d_ws, size_t ws_size,
                              hipStream_t stream) {
    const float* x    = (const float*)d_in[0];
    const int*   src  = (const int*)d_in[1];
    const int*   dst  = (const int*)d_in[2];
    const float* W1   = (const float*)d_in[3];
    const float* al1  = (const float*)d_in[4];
    const float* ar1  = (const float*)d_in[5];
    const float* b1   = (const float*)d_in[6];
    const float* W2   = (const float*)d_in[7];
    const float* al2  = (const float*)d_in[8];
    const float* ar2  = (const float*)d_in[9];
    const float* b2   = (const float*)d_in[10];
    const float* W3   = (const float*)d_in[11];
    const float* al3  = (const float*)d_in[12];
    const float* ar3  = (const float*)d_in[13];
    const float* b3   = (const float*)d_in[14];
    const float* resW3= (const float*)d_in[15];
    float* out = (float*)d_out;

    const int N = in_sizes[0] / 128;
    const int E = in_sizes[1];
    const int TILES16 = (N + 15) / 16;
    const int PT = (TILES16 + 3) & ~3;     // padded to multiple of 4 tiles
    const int NB = PT / 4;                 // GEMM blocks (4 waves/block, 16 rows/wave)

    // workspace layout
    float* fws  = (float*)d_ws;
    float* res3 = fws;                          // N*192 fp32
    float* elb  = res3 + (size_t)N * 192;       // N*6
    float* erb  = elb + (size_t)N * 6;          // N*6
    _Float16* feat_h = (_Float16*)(erb + (size_t)N * 6);  // N*192 f16
    _Float16* xh_hi  = feat_h + (size_t)N * 192;          // PT*2048 (x packed; reused as h2)
    _Float16* xh_lo  = xh_hi + (size_t)PT * 2048;
    _Float16* h1_hi  = xh_lo + (size_t)PT * 2048;
    _Float16* h1_lo  = h1_hi + (size_t)PT * 2048;
    _Float16* wts    = h1_lo + (size_t)PT * 2048;         // 163840 f16
    int* deg       = (int*)(wts + 163840);         // N
    int* row_start = deg + N;                      // N+1
    int* csr_src   = row_start + (N + 1);          // E

    const _Float16* W1h = wts;
    const _Float16* W1l = wts + 16384;
    const _Float16* W2h = wts + 32768;
    const _Float16* W2l = wts + 49152;
    const _Float16* W3h = wts + 65536;            // cols 0..191 of L3 block
    const _Float16* W3l = wts + 65536 + 49152;
    const _Float16* Wrh = W3h + 192 * 128;        // cols 192..383 (resW3)
    const _Float16* Wrl = W3l + 192 * 128;

    // ---- CSR build (by dst) + weight split + x packing ----
    hipMemsetAsync(deg, 0, (size_t)N * sizeof(int), stream);
    hist_kernel<<<dim3((E + 255) / 256), dim3(256), 0, stream>>>(dst, E, deg);
    scan_kernel<<<dim3(1), dim3(1024), 0, stream>>>(deg, row_start, N);
    hipMemsetAsync(deg, 0, (size_t)N * sizeof(int), stream);
    fill_kernel<<<dim3((E + 255) / 256), dim3(256), 0, stream>>>(src, dst, E, row_start, deg, csr_src);
    wsplit_all<<<dim3(320), dim3(256), 0, stream>>>(W1, W2, W3, resW3, wts);
    splitx_kernel<<<dim3((PT * 2048 + 255) / 256), dim3(256), 0, stream>>>(x, xh_hi, xh_lo, N, PT);

    // ---- Layer 1 ----
    mfma_fc<128, 4><<<dim3(NB), dim3(256), 0, stream>>>(
        xh_hi, xh_lo, W1h, W1l, al1, ar1, feat_h, elb, erb, N);
    gat_agg<4, true, false, 256, 0, true><<<dim3(N), dim3(256), 0, stream>>>(
        feat_h, elb, erb, row_start, csr_src, b1,
        nullptr, nullptr, nullptr, nullptr, h1_hi, h1_lo, N);

    // ---- Layer 2 (identity residual = h1, read from packed planes) ----
    mfma_fc<128, 4><<<dim3(NB), dim3(256), 0, stream>>>(
        h1_hi, h1_lo, W2h, W2l, al2, ar2, feat_h, elb, erb, N);
    gat_agg<4, true, false, 256, 1, true><<<dim3(N), dim3(256), 0, stream>>>(
        feat_h, elb, erb, row_start, csr_src, b2,
        nullptr, h1_hi, h1_lo, nullptr, xh_hi, xh_lo, N);   // h2 -> reuse x planes

    // ---- Layer 3: dual GEMM (y=0: W3 feat f16 + logits; y=1: resW3 fp32) ----
    mfma_fc3<<<dim3(NB, 2), dim3(256), 0, stream>>>(
        xh_hi, xh_lo, W3h, W3l, Wrh, Wrl, al3, ar3, feat_h, res3, elb, erb, N);
    gat_agg<6, false, true, 192, 2, false><<<dim3(N), dim3(192), 0, stream>>>(
        feat_h, elb, erb, row_start, csr_src, b3,
        res3, nullptr, nullptr, out, nullptr, nullptr, N);
}

// Round 8
// 578.083 us; speedup vs baseline: 1.4461x; 1.2277x over previous
//
#include <hip/hip_runtime.h>
#include <math.h>

// GAT 3-layer forward on MI355X.
// N=50000 nodes, E=850000 edges (incl self loops), IN=128, HID=OUT=32, HEADS=(4,4,6).
// GEMMs: split-f16 MFMA (hi/lo, 3 mfma), LDS-free; BOTH A and B pre-packed in
// MFMA-fragment order (pack_off) so every wave load is 1KB contiguous (round 7's B
// loads were 256B-strided -> ~16 transactions per load -> latency wall).
// NEVER partial-unroll the tile loop (dynamic acc[] indexing -> scratch spill, round 4).
// Aggregation: shift-free softmax (alpha invariant to max subtraction; logits bounded
// ~|3|), w=exp(leaky) computed once in the logit pass, denominator accumulated in the
// main gather loop. f16x4 gathers, ROW/4 threads per edge group.

typedef _Float16 v8h __attribute__((ext_vector_type(8)));
typedef _Float16 f16x4 __attribute__((ext_vector_type(4)));
typedef float f32x4 __attribute__((ext_vector_type(4)));

// packed fragment offset for row n, k-dim k (128-wide K):
// tile(n/16)*2048 + (k/32)*512 + ((k/8)%4)*128 + (n%16)*8 + k%8
__device__ __host__ inline int pack_off(int n, int k) {
    return ((n >> 4) << 11) | ((k >> 5) << 9) | (((k >> 3) & 3) << 7) | ((n & 15) << 3) | (k & 7);
}

// ---------------- CSR build (by dst) ----------------

__global__ void hist_kernel(const int* __restrict__ dst, int E, int* __restrict__ deg) {
    int i = blockIdx.x * blockDim.x + threadIdx.x;
    if (i < E) atomicAdd(&deg[dst[i]], 1);
}

__global__ void scan_kernel(const int* __restrict__ deg, int* __restrict__ row_start, int n) {
    const int T = 1024;
    __shared__ int sums[T];
    int t = threadIdx.x;
    int chunk = (n + T - 1) / T;
    int begin = t * chunk;
    int finish = begin + chunk; if (finish > n) finish = n;
    int s = 0;
    for (int i = begin; i < finish; i++) s += deg[i];
    sums[t] = s;
    __syncthreads();
    for (int off = 1; off < T; off <<= 1) {
        int u = (t >= off) ? sums[t - off] : 0;
        __syncthreads();
        sums[t] += u;
        __syncthreads();
    }
    int base = (t == 0) ? 0 : sums[t - 1];
    for (int i = begin; i < finish; i++) { row_start[i] = base; base += deg[i]; }
    if (t == T - 1) row_start[n] = sums[T - 1];
}

__global__ void fill_kernel(const int* __restrict__ src, const int* __restrict__ dst, int E,
                            const int* __restrict__ row_start, int* __restrict__ cursor,
                            int* __restrict__ csr_src) {
    int i = blockIdx.x * blockDim.x + threadIdx.x;
    if (i < E) {
        int d = dst[i];
        int pos = atomicAdd(&cursor[d], 1);
        csr_src[row_start[d] + pos] = src[i];
    }
}

// ---------------- weight hi/lo split into PACKED fragment layout ----------------
// W1h@0 W1l@16384 W2h@32768 W2l@49152; L3 combined (cols 0..191 = W3, 192..383 = resW3):
// hi@65536, lo@114688. Within each block: offset = pack_off(col, k).

__global__ void wsplit_all(const float* __restrict__ W1, const float* __restrict__ W2,
                           const float* __restrict__ W3, const float* __restrict__ Wr,
                           _Float16* __restrict__ o) {
    int i = blockIdx.x * blockDim.x + threadIdx.x;
    if (i >= 81920) return;
    float v; int ohi, e, stride;
    if (i < 16384) {
        e = i; int c = e >> 7, k = e & 127;
        v = W1[(size_t)k * 128 + c]; ohi = 0; stride = 16384;
    } else if (i < 32768) {
        e = i - 16384; int c = e >> 7, k = e & 127;
        v = W2[(size_t)k * 128 + c]; ohi = 32768; stride = 16384;
    } else {
        e = i - 32768; int c = e >> 7, k = e & 127;
        v = (c < 192) ? W3[(size_t)k * 192 + c] : Wr[(size_t)k * 192 + (c - 192)];
        ohi = 65536; stride = 49152;
    }
    int c = e >> 7, k = e & 127;
    int po = pack_off(c, k);
    _Float16 hv = (_Float16)v;
    o[ohi + po] = hv;
    o[ohi + stride + po] = (_Float16)(v - (float)hv);
}

// ---------------- x -> packed hi/lo f16 fragment layout ----------------

__global__ void splitx_kernel(const float* __restrict__ x, _Float16* __restrict__ hi,
                              _Float16* __restrict__ lo, int N, int PT) {
    int i = blockIdx.x * blockDim.x + threadIdx.x;
    if (i >= PT * 2048) return;
    int mt = i >> 11, r = i & 2047;
    int q4 = r >> 9, quad = (r >> 7) & 3, ln = (r >> 3) & 15, j = r & 7;
    int n = mt * 16 + ln, k = q4 * 32 + quad * 8 + j;
    float v = (n < N) ? x[(size_t)n * 128 + k] : 0.f;
    _Float16 h = (_Float16)v;
    hi[i] = h;
    lo[i] = (_Float16)(v - (float)h);
}

// ---------------- LDS-free MFMA fc (+ attention logits), layers 1/2 ----------------
// 4 waves/block, wave handles 16 rows (one packed tile) x all CC cols.
// A and B loads are both 1KB-contiguous per wave (packed fragment order).

template <int CC, int H>
__global__ __launch_bounds__(256, 4) void mfma_fc(
    const _Float16* __restrict__ Ahi, const _Float16* __restrict__ Alo,
    const _Float16* __restrict__ Bhi, const _Float16* __restrict__ Blo,
    const float* __restrict__ al, const float* __restrict__ ar,
    _Float16* __restrict__ feat_out,
    float* __restrict__ el, float* __restrict__ er, int N) {
    constexpr int TILES = CC / 16;
    int t = threadIdx.x;
    int wave = t >> 6, lane = t & 63;
    int ln = lane & 15, quad = lane >> 4;
    int mt = blockIdx.x * 4 + wave;

    f32x4 acc[TILES];
    #pragma unroll
    for (int i = 0; i < TILES; i++) acc[i] = (f32x4){0.f, 0.f, 0.f, 0.f};

    const _Float16* pa_h = Ahi + (size_t)mt * 2048 + lane * 8;
    const _Float16* pa_l = Alo + (size_t)mt * 2048 + lane * 8;

    #pragma unroll
    for (int q4 = 0; q4 < 4; q4++) {
        v8h ah = *(const v8h*)(pa_h + q4 * 512);
        v8h av = *(const v8h*)(pa_l + q4 * 512);
        #pragma unroll
        for (int tt = 0; tt < TILES; tt++) {
            size_t boff = (size_t)tt * 2048 + q4 * 512 + lane * 8;
            v8h bh = *(const v8h*)(Bhi + boff);
            v8h bl = *(const v8h*)(Blo + boff);
            acc[tt] = __builtin_amdgcn_mfma_f32_16x16x32_f16(av, bh, acc[tt], 0, 0, 0);
            acc[tt] = __builtin_amdgcn_mfma_f32_16x16x32_f16(ah, bl, acc[tt], 0, 0, 0);
            acc[tt] = __builtin_amdgcn_mfma_f32_16x16x32_f16(ah, bh, acc[tt], 0, 0, 0);
        }
    }

    // C/D layout: col=lane&15, row=quad*4+reg
    #pragma unroll
    for (int tt = 0; tt < TILES; tt++) {
        int n = tt * 16 + ln;
        #pragma unroll
        for (int r = 0; r < 4; r++) {
            int m = mt * 16 + quad * 4 + r;
            if (m < N) feat_out[(size_t)m * CC + n] = (_Float16)acc[tt][r];
        }
    }
    #pragma unroll
    for (int hg = 0; hg < H; hg++) {
        float a0 = al[hg * 32 + ln], a1 = al[hg * 32 + 16 + ln];
        float r0 = ar[hg * 32 + ln], r1 = ar[hg * 32 + 16 + ln];
        #pragma unroll
        for (int r = 0; r < 4; r++) {
            float pl = acc[2 * hg][r] * a0 + acc[2 * hg + 1][r] * a1;
            float pr = acc[2 * hg][r] * r0 + acc[2 * hg + 1][r] * r1;
            #pragma unroll
            for (int off = 1; off < 16; off <<= 1) {
                pl += __shfl_xor(pl, off);
                pr += __shfl_xor(pr, off);
            }
            int m = mt * 16 + quad * 4 + r;
            if (ln == 0 && m < N) {
                el[(size_t)m * H + hg] = pl;
                er[(size_t)m * H + hg] = pr;
            }
        }
    }
}

// ---------------- layer 3: dual grid (y=0: W3 feat f16 + logits; y=1: resW3 fp32) ----------------

__global__ __launch_bounds__(256, 3) void mfma_fc3(
    const _Float16* __restrict__ Ahi, const _Float16* __restrict__ Alo,
    const _Float16* __restrict__ B3h, const _Float16* __restrict__ B3l,
    const _Float16* __restrict__ Brh, const _Float16* __restrict__ Brl,
    const float* __restrict__ al, const float* __restrict__ ar,
    _Float16* __restrict__ feat_out, float* __restrict__ res_out,
    float* __restrict__ el, float* __restrict__ er, int N) {
    constexpr int CC = 192, H = 6, TILES = 12;
    const bool isres = (blockIdx.y == 1);
    const _Float16* __restrict__ Bhi = isres ? Brh : B3h;
    const _Float16* __restrict__ Blo = isres ? Brl : B3l;

    int t = threadIdx.x;
    int wave = t >> 6, lane = t & 63;
    int ln = lane & 15, quad = lane >> 4;
    int mt = blockIdx.x * 4 + wave;

    f32x4 acc[TILES];
    #pragma unroll
    for (int i = 0; i < TILES; i++) acc[i] = (f32x4){0.f, 0.f, 0.f, 0.f};

    const _Float16* pa_h = Ahi + (size_t)mt * 2048 + lane * 8;
    const _Float16* pa_l = Alo + (size_t)mt * 2048 + lane * 8;

    #pragma unroll
    for (int q4 = 0; q4 < 4; q4++) {
        v8h ah = *(const v8h*)(pa_h + q4 * 512);
        v8h av = *(const v8h*)(pa_l + q4 * 512);
        #pragma unroll
        for (int tt = 0; tt < TILES; tt++) {
            size_t boff = (size_t)tt * 2048 + q4 * 512 + lane * 8;
            v8h bh = *(const v8h*)(Bhi + boff);
            v8h bl = *(const v8h*)(Blo + boff);
            acc[tt] = __builtin_amdgcn_mfma_f32_16x16x32_f16(av, bh, acc[tt], 0, 0, 0);
            acc[tt] = __builtin_amdgcn_mfma_f32_16x16x32_f16(ah, bl, acc[tt], 0, 0, 0);
            acc[tt] = __builtin_amdgcn_mfma_f32_16x16x32_f16(ah, bh, acc[tt], 0, 0, 0);
        }
    }

    if (!isres) {
        #pragma unroll
        for (int tt = 0; tt < TILES; tt++) {
            int n = tt * 16 + ln;
            #pragma unroll
            for (int r = 0; r < 4; r++) {
                int m = mt * 16 + quad * 4 + r;
                if (m < N) feat_out[(size_t)m * CC + n] = (_Float16)acc[tt][r];
            }
        }
        #pragma unroll
        for (int hg = 0; hg < H; hg++) {
            float a0 = al[hg * 32 + ln], a1 = al[hg * 32 + 16 + ln];
            float r0 = ar[hg * 32 + ln], r1 = ar[hg * 32 + 16 + ln];
            #pragma unroll
            for (int r = 0; r < 4; r++) {
                float pl = acc[2 * hg][r] * a0 + acc[2 * hg + 1][r] * a1;
                float pr = acc[2 * hg][r] * r0 + acc[2 * hg + 1][r] * r1;
                #pragma unroll
                for (int off = 1; off < 16; off <<= 1) {
                    pl += __shfl_xor(pl, off);
                    pr += __shfl_xor(pr, off);
                }
                int m = mt * 16 + quad * 4 + r;
                if (ln == 0 && m < N) {
                    el[(size_t)m * H + hg] = pl;
                    er[(size_t)m * H + hg] = pr;
                }
            }
        }
    } else {
        #pragma unroll
        for (int tt = 0; tt < TILES; tt++) {
            int n = tt * 16 + ln;
            #pragma unroll
            for (int r = 0; r < 4; r++) {
                int m = mt * 16 + quad * 4 + r;
                if (m < N) res_out[(size_t)m * CC + n] = acc[tt][r];
            }
        }
    }
}

// ---------------- per-node edge aggregate, shift-free softmax ----------------
// Thread = (edge group g, dim quad d4). f16x4 gathers. w = exp(leaky(e)) computed once
// in the logit pass (softmax is shift-invariant; logits bounded). Denominator
// accumulated in-register in the main loop; one writer per (group, head).
// RES: 0 none, 1 packed hi/lo, 2 plain fp32. PACK: emit packed hi/lo planes.

template <int H, bool RELU, bool MEAN, int NT, int RES, bool PACK>
__global__ __launch_bounds__(NT) void gat_agg(
        const _Float16* __restrict__ feat, const float* __restrict__ el,
        const float* __restrict__ er, const int* __restrict__ row_start,
        const int* __restrict__ csr_src, const float* __restrict__ bias,
        const float* __restrict__ res_plain,
        const _Float16* __restrict__ res_hi, const _Float16* __restrict__ res_lo,
        float* __restrict__ out, _Float16* __restrict__ out_hi, _Float16* __restrict__ out_lo,
        int N) {
    constexpr int ROW = H * 32;
    constexpr int HW = ROW / 4;      // threads per edge group (dim quads)
    constexpr int G = NT / HW;       // edge groups
    constexpr int CHUNK = 128;
    constexpr int SWP = H + 1;       // padded s_w stride (bank-conflict-free reads)
    static_assert(NT % HW == 0 && NT >= H * 32, "layout");

    __shared__ int   s_src[CHUNK];
    __shared__ float s_w[CHUNK * SWP];
    __shared__ float s_er[H];
    __shared__ float s_dnm[G][H];
    __shared__ float s_part[G][ROW];
    __shared__ float s_red[MEAN ? ROW : 1];

    int n = blockIdx.x;
    int t = threadIdx.x;
    int d4 = t % HW;        // dim quad: dims 4*d4 .. 4*d4+3
    int g  = t / HW;        // edge group
    int hd = d4 >> 3;       // head of this dim quad

    int start = row_start[n];
    int end   = row_start[n + 1];

    if (t < H) s_er[t] = er[(size_t)n * H + t];
    __syncthreads();

    float a0 = 0.f, a1 = 0.f, a2 = 0.f, a3 = 0.f, dacc = 0.f;
    for (int cs = start; cs < end; cs += CHUNK) {
        int c = end - cs; if (c > CHUNK) c = CHUNK;

        for (int i = t; i < c; i += NT) s_src[i] = csr_src[cs + i];
        __syncthreads();

        // logits -> w = exp(leaky(el[s]+er[n])) (coalesced el gathers, L2-hot table)
        for (int i = t; i < c * H; i += NT) {
            int j = i / H, hh = i - j * H;
            float e = el[(size_t)s_src[j] * H + hh] + s_er[hh];
            e = (e >= 0.f) ? e : 0.2f * e;
            s_w[j * SWP + hh] = __expf(e);
        }
        __syncthreads();

        int j = g;
        for (; j + G < c; j += 2 * G) {
            int s0 = s_src[j], s1 = s_src[j + G];
            float w0 = s_w[j * SWP + hd], w1 = s_w[(j + G) * SWP + hd];
            f16x4 v0 = *(const f16x4*)(feat + (size_t)s0 * ROW + 4 * d4);
            f16x4 v1 = *(const f16x4*)(feat + (size_t)s1 * ROW + 4 * d4);
            a0 += w0 * (float)v0.x + w1 * (float)v1.x;
            a1 += w0 * (float)v0.y + w1 * (float)v1.y;
            a2 += w0 * (float)v0.z + w1 * (float)v1.z;
            a3 += w0 * (float)v0.w + w1 * (float)v1.w;
            dacc += w0 + w1;
        }
        if (j < c) {
            int s0 = s_src[j];
            float w0 = s_w[j * SWP + hd];
            f16x4 v0 = *(const f16x4*)(feat + (size_t)s0 * ROW + 4 * d4);
            a0 += w0 * (float)v0.x;
            a1 += w0 * (float)v0.y;
            a2 += w0 * (float)v0.z;
            a3 += w0 * (float)v0.w;
            dacc += w0;
        }
        __syncthreads();   // protect s_src/s_w before next chunk
    }

    // publish partials
    s_part[g][4 * d4]     = a0;
    s_part[g][4 * d4 + 1] = a1;
    s_part[g][4 * d4 + 2] = a2;
    s_part[g][4 * d4 + 3] = a3;
    if ((d4 & 7) == 0) s_dnm[g][hd] = dacc;
    __syncthreads();

    float rst = 0.f;
    if (t < ROW) {
        float sum = 0.f;
        #pragma unroll
        for (int gg = 0; gg < G; gg++) sum += s_part[gg][t];
        int h = t >> 5;
        float den = 0.f;
        #pragma unroll
        for (int gg = 0; gg < G; gg++) den += s_dnm[gg][h];
        rst = sum / fmaxf(den, 1e-9f);
        rst += bias[t];
        if constexpr (RES == 1) {
            int off = pack_off(n, t);
            rst += (float)res_hi[off] + (float)res_lo[off];
        } else if constexpr (RES == 2) {
            rst += res_plain[(size_t)n * ROW + t];
        }
        if (RELU) rst = fmaxf(rst, 0.f);
        if constexpr (PACK) {
            int off = pack_off(n, t);
            _Float16 hh = (_Float16)rst;
            out_hi[off] = hh;
            out_lo[off] = (_Float16)(rst - (float)hh);
        } else if constexpr (!MEAN) {
            out[(size_t)n * ROW + t] = rst;
        }
    }
    if constexpr (MEAN) {
        if (t < ROW) s_red[t] = rst;
        __syncthreads();
        if (t < 32) {
            float v = 0.f;
            #pragma unroll
            for (int hh = 0; hh < H; hh++) v += s_red[hh * 32 + t];
            out[(size_t)n * 32 + t] = v * (1.0f / H);
        }
    }
}

// ---------------- launch ----------------

extern "C" void kernel_launch(void* const* d_in, const int* in_sizes, int n_in,
                              void* d_out, int out_size, void* d_ws, size_t ws_size,
                              hipStream_t stream) {
    const float* x    = (const float*)d_in[0];
    const int*   src  = (const int*)d_in[1];
    const int*   dst  = (const int*)d_in[2];
    const float* W1   = (const float*)d_in[3];
    const float* al1  = (const float*)d_in[4];
    const float* ar1  = (const float*)d_in[5];
    const float* b1   = (const float*)d_in[6];
    const float* W2   = (const float*)d_in[7];
    const float* al2  = (const float*)d_in[8];
    const float* ar2  = (const float*)d_in[9];
    const float* b2   = (const float*)d_in[10];
    const float* W3   = (const float*)d_in[11];
    const float* al3  = (const float*)d_in[12];
    const float* ar3  = (const float*)d_in[13];
    const float* b3   = (const float*)d_in[14];
    const float* resW3= (const float*)d_in[15];
    float* out = (float*)d_out;

    const int N = in_sizes[0] / 128;
    const int E = in_sizes[1];
    const int TILES16 = (N + 15) / 16;
    const int PT = (TILES16 + 3) & ~3;     // padded to multiple of 4 tiles
    const int NB = PT / 4;                 // GEMM blocks (4 waves/block, 16 rows/wave)

    // workspace layout
    float* fws  = (float*)d_ws;
    float* res3 = fws;                          // N*192 fp32
    float* elb  = res3 + (size_t)N * 192;       // N*6
    float* erb  = elb + (size_t)N * 6;          // N*6
    _Float16* feat_h = (_Float16*)(erb + (size_t)N * 6);  // N*192 f16
    _Float16* xh_hi  = feat_h + (size_t)N * 192;          // PT*2048 (x packed; reused as h2)
    _Float16* xh_lo  = xh_hi + (size_t)PT * 2048;
    _Float16* h1_hi  = xh_lo + (size_t)PT * 2048;
    _Float16* h1_lo  = h1_hi + (size_t)PT * 2048;
    _Float16* wts    = h1_lo + (size_t)PT * 2048;         // 163840 f16
    int* deg       = (int*)(wts + 163840);         // N
    int* row_start = deg + N;                      // N+1
    int* csr_src   = row_start + (N + 1);          // E

    const _Float16* W1h = wts;
    const _Float16* W1l = wts + 16384;
    const _Float16* W2h = wts + 32768;
    const _Float16* W2l = wts + 49152;
    const _Float16* W3h = wts + 65536;            // packed tiles 0..11 (cols 0..191)
    const _Float16* W3l = wts + 65536 + 49152;
    const _Float16* Wrh = W3h + 192 * 128;        // packed tiles 12..23 (resW3)
    const _Float16* Wrl = W3l + 192 * 128;

    // ---- CSR build (by dst) + weight split + x packing ----
    hipMemsetAsync(deg, 0, (size_t)N * sizeof(int), stream);
    hist_kernel<<<dim3((E + 255) / 256), dim3(256), 0, stream>>>(dst, E, deg);
    scan_kernel<<<dim3(1), dim3(1024), 0, stream>>>(deg, row_start, N);
    hipMemsetAsync(deg, 0, (size_t)N * sizeof(int), stream);
    fill_kernel<<<dim3((E + 255) / 256), dim3(256), 0, stream>>>(src, dst, E, row_start, deg, csr_src);
    wsplit_all<<<dim3(320), dim3(256), 0, stream>>>(W1, W2, W3, resW3, wts);
    splitx_kernel<<<dim3((PT * 2048 + 255) / 256), dim3(256), 0, stream>>>(x, xh_hi, xh_lo, N, PT);

    // ---- Layer 1 ----
    mfma_fc<128, 4><<<dim3(NB), dim3(256), 0, stream>>>(
        xh_hi, xh_lo, W1h, W1l, al1, ar1, feat_h, elb, erb, N);
    gat_agg<4, true, false, 256, 0, true><<<dim3(N), dim3(256), 0, stream>>>(
        feat_h, elb, erb, row_start, csr_src, b1,
        nullptr, nullptr, nullptr, nullptr, h1_hi, h1_lo, N);

    // ---- Layer 2 (identity residual = h1, read from packed planes) ----
    mfma_fc<128, 4><<<dim3(NB), dim3(256), 0, stream>>>(
        h1_hi, h1_lo, W2h, W2l, al2, ar2, feat_h, elb, erb, N);
    gat_agg<4, true, false, 256, 1, true><<<dim3(N), dim3(256), 0, stream>>>(
        feat_h, elb, erb, row_start, csr_src, b2,
        nullptr, h1_hi, h1_lo, nullptr, xh_hi, xh_lo, N);   // h2 -> reuse x planes

    // ---- Layer 3: dual GEMM (y=0: W3 feat f16 + logits; y=1: resW3 fp32) ----
    mfma_fc3<<<dim3(NB, 2), dim3(256), 0, stream>>>(
        xh_hi, xh_lo, W3h, W3l, Wrh, Wrl, al3, ar3, feat_h, res3, elb, erb, N);
    gat_agg<6, false, true, 192, 2, false><<<dim3(N), dim3(192), 0, stream>>>(
        feat_h, elb, erb, row_start, csr_src, b3,
        res3, nullptr, nullptr, out, nullptr, nullptr, N);
}

// Round 10
// 511.919 us; speedup vs baseline: 1.6331x; 1.1292x over previous
//
#include <hip/hip_runtime.h>
#include <math.h>

// GAT 3-layer forward on MI355X.
// N=50000 nodes, E=850000 edges (incl self loops), IN=128, HID=OUT=32, HEADS=(4,4,6).
// GEMMs: split-f16 MFMA (hi/lo, 3 mfma), LDS-free; A and B pre-packed in MFMA-fragment
// order (pack_off) -> every wave load is 1KB contiguous. NEVER partial-unroll the tile
// loop (dynamic acc[] indexing -> scratch spill, round 4).
// Aggregation: ONE WAVE PER NODE, zero LDS, zero barriers. Edge src ids are loaded
// DIRECTLY by each lane (group lanes hit the same address -> broadcast; L1-hot line).
// Round 9's register-staging + __shfl broadcast corrupted results (exec-mask-sensitive
// bpermute under divergence) -> all shuffles now run unconditionally, stores guarded.
// Shift-free softmax (logits bounded); denominator in registers.

typedef _Float16 v8h __attribute__((ext_vector_type(8)));
typedef _Float16 f16x4 __attribute__((ext_vector_type(4)));
typedef float f32x4 __attribute__((ext_vector_type(4)));

// packed fragment offset for row n, k-dim k (128-wide K):
__device__ __host__ inline int pack_off(int n, int k) {
    return ((n >> 4) << 11) | ((k >> 5) << 9) | (((k >> 3) & 3) << 7) | ((n & 15) << 3) | (k & 7);
}

// ---------------- CSR build (by dst) ----------------

__global__ void hist_kernel(const int* __restrict__ dst, int E, int* __restrict__ deg) {
    int i = blockIdx.x * blockDim.x + threadIdx.x;
    if (i < E) atomicAdd(&deg[dst[i]], 1);
}

__global__ void scan_kernel(const int* __restrict__ deg, int* __restrict__ row_start, int n) {
    const int T = 1024;
    __shared__ int sums[T];
    int t = threadIdx.x;
    int chunk = (n + T - 1) / T;
    int begin = t * chunk;
    int finish = begin + chunk; if (finish > n) finish = n;
    int s = 0;
    for (int i = begin; i < finish; i++) s += deg[i];
    sums[t] = s;
    __syncthreads();
    for (int off = 1; off < T; off <<= 1) {
        int u = (t >= off) ? sums[t - off] : 0;
        __syncthreads();
        sums[t] += u;
        __syncthreads();
    }
    int base = (t == 0) ? 0 : sums[t - 1];
    for (int i = begin; i < finish; i++) { row_start[i] = base; base += deg[i]; }
    if (t == T - 1) row_start[n] = sums[T - 1];
}

__global__ void fill_kernel(const int* __restrict__ src, const int* __restrict__ dst, int E,
                            const int* __restrict__ row_start, int* __restrict__ cursor,
                            int* __restrict__ csr_src) {
    int i = blockIdx.x * blockDim.x + threadIdx.x;
    if (i < E) {
        int d = dst[i];
        int pos = atomicAdd(&cursor[d], 1);
        csr_src[row_start[d] + pos] = src[i];
    }
}

// ---------------- weight hi/lo split into PACKED fragment layout ----------------

__global__ void wsplit_all(const float* __restrict__ W1, const float* __restrict__ W2,
                           const float* __restrict__ W3, const float* __restrict__ Wr,
                           _Float16* __restrict__ o) {
    int i = blockIdx.x * blockDim.x + threadIdx.x;
    if (i >= 81920) return;
    float v; int ohi, e, stride;
    if (i < 16384) {
        e = i; int c = e >> 7, k = e & 127;
        v = W1[(size_t)k * 128 + c]; ohi = 0; stride = 16384;
    } else if (i < 32768) {
        e = i - 16384; int c = e >> 7, k = e & 127;
        v = W2[(size_t)k * 128 + c]; ohi = 32768; stride = 16384;
    } else {
        e = i - 32768; int c = e >> 7, k = e & 127;
        v = (c < 192) ? W3[(size_t)k * 192 + c] : Wr[(size_t)k * 192 + (c - 192)];
        ohi = 65536; stride = 49152;
    }
    int c = e >> 7, k = e & 127;
    int po = pack_off(c, k);
    _Float16 hv = (_Float16)v;
    o[ohi + po] = hv;
    o[ohi + stride + po] = (_Float16)(v - (float)hv);
}

// ---------------- x -> packed hi/lo f16 fragment layout ----------------

__global__ void splitx_kernel(const float* __restrict__ x, _Float16* __restrict__ hi,
                              _Float16* __restrict__ lo, int N, int PT) {
    int i = blockIdx.x * blockDim.x + threadIdx.x;
    if (i >= PT * 2048) return;
    int mt = i >> 11, r = i & 2047;
    int q4 = r >> 9, quad = (r >> 7) & 3, ln = (r >> 3) & 15, j = r & 7;
    int n = mt * 16 + ln, k = q4 * 32 + quad * 8 + j;
    float v = (n < N) ? x[(size_t)n * 128 + k] : 0.f;
    _Float16 h = (_Float16)v;
    hi[i] = h;
    lo[i] = (_Float16)(v - (float)h);
}

// ---------------- LDS-free MFMA fc (+ attention logits), layers 1/2 ----------------

template <int CC, int H>
__global__ __launch_bounds__(256, 4) void mfma_fc(
    const _Float16* __restrict__ Ahi, const _Float16* __restrict__ Alo,
    const _Float16* __restrict__ Bhi, const _Float16* __restrict__ Blo,
    const float* __restrict__ al, const float* __restrict__ ar,
    _Float16* __restrict__ feat_out,
    float* __restrict__ el, float* __restrict__ er, int N) {
    constexpr int TILES = CC / 16;
    int t = threadIdx.x;
    int wave = t >> 6, lane = t & 63;
    int ln = lane & 15, quad = lane >> 4;
    int mt = blockIdx.x * 4 + wave;

    f32x4 acc[TILES];
    #pragma unroll
    for (int i = 0; i < TILES; i++) acc[i] = (f32x4){0.f, 0.f, 0.f, 0.f};

    const _Float16* pa_h = Ahi + (size_t)mt * 2048 + lane * 8;
    const _Float16* pa_l = Alo + (size_t)mt * 2048 + lane * 8;

    #pragma unroll
    for (int q4 = 0; q4 < 4; q4++) {
        v8h ah = *(const v8h*)(pa_h + q4 * 512);
        v8h av = *(const v8h*)(pa_l + q4 * 512);
        #pragma unroll
        for (int tt = 0; tt < TILES; tt++) {
            size_t boff = (size_t)tt * 2048 + q4 * 512 + lane * 8;
            v8h bh = *(const v8h*)(Bhi + boff);
            v8h bl = *(const v8h*)(Blo + boff);
            acc[tt] = __builtin_amdgcn_mfma_f32_16x16x32_f16(av, bh, acc[tt], 0, 0, 0);
            acc[tt] = __builtin_amdgcn_mfma_f32_16x16x32_f16(ah, bl, acc[tt], 0, 0, 0);
            acc[tt] = __builtin_amdgcn_mfma_f32_16x16x32_f16(ah, bh, acc[tt], 0, 0, 0);
        }
    }

    #pragma unroll
    for (int tt = 0; tt < TILES; tt++) {
        int n = tt * 16 + ln;
        #pragma unroll
        for (int r = 0; r < 4; r++) {
            int m = mt * 16 + quad * 4 + r;
            if (m < N) feat_out[(size_t)m * CC + n] = (_Float16)acc[tt][r];
        }
    }
    #pragma unroll
    for (int hg = 0; hg < H; hg++) {
        float a0 = al[hg * 32 + ln], a1 = al[hg * 32 + 16 + ln];
        float r0 = ar[hg * 32 + ln], r1 = ar[hg * 32 + 16 + ln];
        #pragma unroll
        for (int r = 0; r < 4; r++) {
            float pl = acc[2 * hg][r] * a0 + acc[2 * hg + 1][r] * a1;
            float pr = acc[2 * hg][r] * r0 + acc[2 * hg + 1][r] * r1;
            #pragma unroll
            for (int off = 1; off < 16; off <<= 1) {
                pl += __shfl_xor(pl, off);
                pr += __shfl_xor(pr, off);
            }
            int m = mt * 16 + quad * 4 + r;
            if (ln == 0 && m < N) {
                el[(size_t)m * H + hg] = pl;
                er[(size_t)m * H + hg] = pr;
            }
        }
    }
}

// ---------------- layer 3: dual grid (y=0: W3 feat f16 + logits; y=1: resW3 fp32) ----------------

__global__ __launch_bounds__(256, 3) void mfma_fc3(
    const _Float16* __restrict__ Ahi, const _Float16* __restrict__ Alo,
    const _Float16* __restrict__ B3h, const _Float16* __restrict__ B3l,
    const _Float16* __restrict__ Brh, const _Float16* __restrict__ Brl,
    const float* __restrict__ al, const float* __restrict__ ar,
    _Float16* __restrict__ feat_out, float* __restrict__ res_out,
    float* __restrict__ el, float* __restrict__ er, int N) {
    constexpr int CC = 192, H = 6, TILES = 12;
    const bool isres = (blockIdx.y == 1);
    const _Float16* __restrict__ Bhi = isres ? Brh : B3h;
    const _Float16* __restrict__ Blo = isres ? Brl : B3l;

    int t = threadIdx.x;
    int wave = t >> 6, lane = t & 63;
    int ln = lane & 15, quad = lane >> 4;
    int mt = blockIdx.x * 4 + wave;

    f32x4 acc[TILES];
    #pragma unroll
    for (int i = 0; i < TILES; i++) acc[i] = (f32x4){0.f, 0.f, 0.f, 0.f};

    const _Float16* pa_h = Ahi + (size_t)mt * 2048 + lane * 8;
    const _Float16* pa_l = Alo + (size_t)mt * 2048 + lane * 8;

    #pragma unroll
    for (int q4 = 0; q4 < 4; q4++) {
        v8h ah = *(const v8h*)(pa_h + q4 * 512);
        v8h av = *(const v8h*)(pa_l + q4 * 512);
        #pragma unroll
        for (int tt = 0; tt < TILES; tt++) {
            size_t boff = (size_t)tt * 2048 + q4 * 512 + lane * 8;
            v8h bh = *(const v8h*)(Bhi + boff);
            v8h bl = *(const v8h*)(Blo + boff);
            acc[tt] = __builtin_amdgcn_mfma_f32_16x16x32_f16(av, bh, acc[tt], 0, 0, 0);
            acc[tt] = __builtin_amdgcn_mfma_f32_16x16x32_f16(ah, bl, acc[tt], 0, 0, 0);
            acc[tt] = __builtin_amdgcn_mfma_f32_16x16x32_f16(ah, bh, acc[tt], 0, 0, 0);
        }
    }

    if (!isres) {
        #pragma unroll
        for (int tt = 0; tt < TILES; tt++) {
            int n = tt * 16 + ln;
            #pragma unroll
            for (int r = 0; r < 4; r++) {
                int m = mt * 16 + quad * 4 + r;
                if (m < N) feat_out[(size_t)m * CC + n] = (_Float16)acc[tt][r];
            }
        }
        #pragma unroll
        for (int hg = 0; hg < H; hg++) {
            float a0 = al[hg * 32 + ln], a1 = al[hg * 32 + 16 + ln];
            float r0 = ar[hg * 32 + ln], r1 = ar[hg * 32 + 16 + ln];
            #pragma unroll
            for (int r = 0; r < 4; r++) {
                float pl = acc[2 * hg][r] * a0 + acc[2 * hg + 1][r] * a1;
                float pr = acc[2 * hg][r] * r0 + acc[2 * hg + 1][r] * r1;
                #pragma unroll
                for (int off = 1; off < 16; off <<= 1) {
                    pl += __shfl_xor(pl, off);
                    pr += __shfl_xor(pr, off);
                }
                int m = mt * 16 + quad * 4 + r;
                if (ln == 0 && m < N) {
                    el[(size_t)m * H + hg] = pl;
                    er[(size_t)m * H + hg] = pr;
                }
            }
        }
    } else {
        #pragma unroll
        for (int tt = 0; tt < TILES; tt++) {
            int n = tt * 16 + ln;
            #pragma unroll
            for (int r = 0; r < 4; r++) {
                int m = mt * 16 + quad * 4 + r;
                if (m < N) res_out[(size_t)m * CC + n] = acc[tt][r];
            }
        }
    }
}

// ---------------- per-node aggregate: ONE WAVE PER NODE, no LDS, no barriers ----------------
// Lane = (edge group g, dim quad d4). Each lane loads csr_src[j] directly (group lanes
// hit the same address -> broadcast). 2x unrolled: two edges' gather chains in flight.
// All shuffles (xor-reduce, head-mean) execute unconditionally; only stores guarded.
// RES: 0 none, 1 packed hi/lo, 2 plain fp32. PACK: emit packed hi/lo planes.

template <int H, bool RELU, bool MEAN, int RES, bool PACK>
__global__ __launch_bounds__(256) void gat_agg_wave(
        const _Float16* __restrict__ feat, const float* __restrict__ el,
        const float* __restrict__ er, const int* __restrict__ row_start,
        const int* __restrict__ csr_src, const float* __restrict__ bias,
        const float* __restrict__ res_plain,
        const _Float16* __restrict__ res_hi, const _Float16* __restrict__ res_lo,
        float* __restrict__ out, _Float16* __restrict__ out_hi, _Float16* __restrict__ out_lo,
        int N) {
    constexpr int ROW = H * 32;
    constexpr int LPG = ROW / 4;          // lanes per edge group (32 for H=4, 48 for H=6)
    constexpr int G   = 64 / LPG;         // edge groups (2 for H=4, 1 for H=6)
    int wv = threadIdx.x >> 6, lane = threadIdx.x & 63;
    int n = blockIdx.x * 4 + wv;
    if (n >= N) return;

    int d4 = lane % LPG;                  // dim quad: dims 4*d4 .. 4*d4+3
    int g  = lane / LPG;                  // edge group (g >= G -> idle in gather)
    int hd = d4 >> 3;                     // head of this lane's dims

    int start = row_start[n], end = row_start[n + 1];
    float er_hd = er[(size_t)n * H + hd];
    const _Float16* fbase = feat + 4 * d4;

    float a0 = 0.f, a1 = 0.f, a2 = 0.f, a3 = 0.f, wsum = 0.f;

    int j = (g < G) ? (start + g) : end;
    for (; j + G < end; j += 2 * G) {
        int s0 = csr_src[j];
        int s1 = csr_src[j + G];
        float e0 = el[(size_t)s0 * H + hd] + er_hd;
        float e1 = el[(size_t)s1 * H + hd] + er_hd;
        e0 = (e0 >= 0.f) ? e0 : 0.2f * e0;
        e1 = (e1 >= 0.f) ? e1 : 0.2f * e1;
        float w0 = __expf(e0);
        float w1 = __expf(e1);
        f16x4 v0 = *(const f16x4*)(fbase + (size_t)s0 * ROW);
        f16x4 v1 = *(const f16x4*)(fbase + (size_t)s1 * ROW);
        wsum += w0 + w1;
        a0 += w0 * (float)v0.x + w1 * (float)v1.x;
        a1 += w0 * (float)v0.y + w1 * (float)v1.y;
        a2 += w0 * (float)v0.z + w1 * (float)v1.z;
        a3 += w0 * (float)v0.w + w1 * (float)v1.w;
    }
    if (j < end) {
        int s0 = csr_src[j];
        float e0 = el[(size_t)s0 * H + hd] + er_hd;
        e0 = (e0 >= 0.f) ? e0 : 0.2f * e0;
        float w0 = __expf(e0);
        f16x4 v0 = *(const f16x4*)(fbase + (size_t)s0 * ROW);
        wsum += w0;
        a0 += w0 * (float)v0.x;
        a1 += w0 * (float)v0.y;
        a2 += w0 * (float)v0.z;
        a3 += w0 * (float)v0.w;
    }

    if constexpr (G == 2) {               // executed by ALL lanes (no divergence)
        a0 += __shfl_xor(a0, 32);
        a1 += __shfl_xor(a1, 32);
        a2 += __shfl_xor(a2, 32);
        a3 += __shfl_xor(a3, 32);
        wsum += __shfl_xor(wsum, 32);
    }

    // epilogue computed by ALL lanes; only stores are guarded.
    float den = fmaxf(wsum, 1e-9f);
    float4 bv = *(const float4*)(bias + 4 * d4);
    float r0 = a0 / den + bv.x;
    float r1 = a1 / den + bv.y;
    float r2 = a2 / den + bv.z;
    float r3 = a3 / den + bv.w;
    if constexpr (RES == 1) {
        int off = pack_off(n, 4 * d4);
        f16x4 rh = *(const f16x4*)(res_hi + off);
        f16x4 rl = *(const f16x4*)(res_lo + off);
        r0 += (float)rh.x + (float)rl.x;
        r1 += (float)rh.y + (float)rl.y;
        r2 += (float)rh.z + (float)rl.z;
        r3 += (float)rh.w + (float)rl.w;
    } else if constexpr (RES == 2) {
        float4 rv = *(const float4*)(res_plain + (size_t)n * ROW + 4 * d4);
        r0 += rv.x; r1 += rv.y; r2 += rv.z; r3 += rv.w;
    }
    if constexpr (RELU) {
        r0 = fmaxf(r0, 0.f); r1 = fmaxf(r1, 0.f);
        r2 = fmaxf(r2, 0.f); r3 = fmaxf(r3, 0.f);
    }

    if constexpr (PACK) {
        if (lane < LPG) {
            int off = pack_off(n, 4 * d4);
            _Float16 h0 = (_Float16)r0, h1 = (_Float16)r1, h2 = (_Float16)r2, h3 = (_Float16)r3;
            *(f16x4*)(out_hi + off) = (f16x4){h0, h1, h2, h3};
            *(f16x4*)(out_lo + off) = (f16x4){(_Float16)(r0 - (float)h0), (_Float16)(r1 - (float)h1),
                                              (_Float16)(r2 - (float)h2), (_Float16)(r3 - (float)h3)};
        }
    } else if constexpr (MEAN) {
        // head-mean: writer lanes (h=0, q<8) need sum over heads hh of lane q+8*hh.
        int q = d4 & 7;
        float s0 = r0, s1 = r1, s2 = r2, s3 = r3;
        #pragma unroll
        for (int hh = 1; hh < H; hh++) {   // executed by ALL lanes
            s0 += __shfl(r0, q + 8 * hh);
            s1 += __shfl(r1, q + 8 * hh);
            s2 += __shfl(r2, q + 8 * hh);
            s3 += __shfl(r3, q + 8 * hh);
        }
        if (lane < 8) {                    // lane==d4==q<8, head 0
            const float sc = 1.0f / H;
            *(float4*)(out + (size_t)n * 32 + 4 * lane) =
                make_float4(s0 * sc, s1 * sc, s2 * sc, s3 * sc);
        }
    } else {
        if (lane < LPG)
            *(float4*)(out + (size_t)n * ROW + 4 * d4) = make_float4(r0, r1, r2, r3);
    }
}

// ---------------- launch ----------------

extern "C" void kernel_launch(void* const* d_in, const int* in_sizes, int n_in,
                              void* d_out, int out_size, void* d_ws, size_t ws_size,
                              hipStream_t stream) {
    const float* x    = (const float*)d_in[0];
    const int*   src  = (const int*)d_in[1];
    const int*   dst  = (const int*)d_in[2];
    const float* W1   = (const float*)d_in[3];
    const float* al1  = (const float*)d_in[4];
    const float* ar1  = (const float*)d_in[5];
    const float* b1   = (const float*)d_in[6];
    const float* W2   = (const float*)d_in[7];
    const float* al2  = (const float*)d_in[8];
    const float* ar2  = (const float*)d_in[9];
    const float* b2   = (const float*)d_in[10];
    const float* W3   = (const float*)d_in[11];
    const float* al3  = (const float*)d_in[12];
    const float* ar3  = (const float*)d_in[13];
    const float* b3   = (const float*)d_in[14];
    const float* resW3= (const float*)d_in[15];
    float* out = (float*)d_out;

    const int N = in_sizes[0] / 128;
    const int E = in_sizes[1];
    const int TILES16 = (N + 15) / 16;
    const int PT = (TILES16 + 3) & ~3;
    const int NB = PT / 4;

    // workspace layout
    float* fws  = (float*)d_ws;
    float* res3 = fws;                          // N*192 fp32
    float* elb  = res3 + (size_t)N * 192;       // N*6
    float* erb  = elb + (size_t)N * 6;          // N*6
    _Float16* feat_h = (_Float16*)(erb + (size_t)N * 6);  // N*192 f16
    _Float16* xh_hi  = feat_h + (size_t)N * 192;          // PT*2048 (x packed; reused as h2)
    _Float16* xh_lo  = xh_hi + (size_t)PT * 2048;
    _Float16* h1_hi  = xh_lo + (size_t)PT * 2048;
    _Float16* h1_lo  = h1_hi + (size_t)PT * 2048;
    _Float16* wts    = h1_lo + (size_t)PT * 2048;         // 163840 f16
    int* deg       = (int*)(wts + 163840);
    int* row_start = deg + N;
    int* csr_src   = row_start + (N + 1);

    const _Float16* W1h = wts;
    const _Float16* W1l = wts + 16384;
    const _Float16* W2h = wts + 32768;
    const _Float16* W2l = wts + 49152;
    const _Float16* W3h = wts + 65536;
    const _Float16* W3l = wts + 65536 + 49152;
    const _Float16* Wrh = W3h + 192 * 128;
    const _Float16* Wrl = W3l + 192 * 128;

    // ---- CSR build (by dst) + weight split + x packing ----
    hipMemsetAsync(deg, 0, (size_t)N * sizeof(int), stream);
    hist_kernel<<<dim3((E + 255) / 256), dim3(256), 0, stream>>>(dst, E, deg);
    scan_kernel<<<dim3(1), dim3(1024), 0, stream>>>(deg, row_start, N);
    hipMemsetAsync(deg, 0, (size_t)N * sizeof(int), stream);
    fill_kernel<<<dim3((E + 255) / 256), dim3(256), 0, stream>>>(src, dst, E, row_start, deg, csr_src);
    wsplit_all<<<dim3(320), dim3(256), 0, stream>>>(W1, W2, W3, resW3, wts);
    splitx_kernel<<<dim3((PT * 2048 + 255) / 256), dim3(256), 0, stream>>>(x, xh_hi, xh_lo, N, PT);

    dim3 ab((N + 3) / 4);

    // ---- Layer 1 ----
    mfma_fc<128, 4><<<dim3(NB), dim3(256), 0, stream>>>(
        xh_hi, xh_lo, W1h, W1l, al1, ar1, feat_h, elb, erb, N);
    gat_agg_wave<4, true, false, 0, true><<<ab, dim3(256), 0, stream>>>(
        feat_h, elb, erb, row_start, csr_src, b1,
        nullptr, nullptr, nullptr, nullptr, h1_hi, h1_lo, N);

    // ---- Layer 2 (identity residual = h1 packed planes) ----
    mfma_fc<128, 4><<<dim3(NB), dim3(256), 0, stream>>>(
        h1_hi, h1_lo, W2h, W2l, al2, ar2, feat_h, elb, erb, N);
    gat_agg_wave<4, true, false, 1, true><<<ab, dim3(256), 0, stream>>>(
        feat_h, elb, erb, row_start, csr_src, b2,
        nullptr, h1_hi, h1_lo, nullptr, xh_hi, xh_lo, N);   // h2 -> reuse x planes

    // ---- Layer 3: dual GEMM, then mean-agg ----
    mfma_fc3<<<dim3(NB, 2), dim3(256), 0, stream>>>(
        xh_hi, xh_lo, W3h, W3l, Wrh, Wrl, al3, ar3, feat_h, res3, elb, erb, N);
    gat_agg_wave<6, false, true, 2, false><<<ab, dim3(256), 0, stream>>>(
        feat_h, elb, erb, row_start, csr_src, b3,
        res3, nullptr, nullptr, out, nullptr, nullptr, N);
}

// Round 11
// 446.129 us; speedup vs baseline: 1.8739x; 1.1475x over previous
//
#include <hip/hip_runtime.h>
#include <math.h>

// GAT 3-layer forward on MI355X.
// N=50000 nodes, E=850000 edges (incl self loops), IN=128, HID=OUT=32, HEADS=(4,4,6).
// GEMMs: split-f16 MFMA (hi/lo, 3 mfma), LDS-free; A and B pre-packed in MFMA-fragment
// order (pack_off) -> every wave load is 1KB contiguous. NEVER partial-unroll the tile
// loop (dynamic acc[] indexing -> scratch spill, round 4).
// Aggregation: ONE WAVE PER NODE, zero LDS, zero barriers (round 10, passing).
// CSR prefix scan: 3-phase multi-block (round 10's single-block scan was 77us on 1 CU).

typedef _Float16 v8h __attribute__((ext_vector_type(8)));
typedef _Float16 f16x4 __attribute__((ext_vector_type(4)));
typedef float f32x4 __attribute__((ext_vector_type(4)));

// packed fragment offset for row n, k-dim k (128-wide K):
__device__ __host__ inline int pack_off(int n, int k) {
    return ((n >> 4) << 11) | ((k >> 5) << 9) | (((k >> 3) & 3) << 7) | ((n & 15) << 3) | (k & 7);
}

// ---------------- CSR build (by dst) ----------------

__global__ void hist_kernel(const int* __restrict__ dst, int E, int* __restrict__ deg) {
    int i = blockIdx.x * blockDim.x + threadIdx.x;
    if (i < E) atomicAdd(&deg[dst[i]], 1);
}

// ---- 3-phase exclusive scan of deg[n] -> row_start[n+1] (2048 elems per block) ----

__global__ void scan_phaseA(const int* __restrict__ deg, int n, int* __restrict__ bsum) {
    __shared__ int red[4];
    int t = threadIdx.x;
    int base = blockIdx.x * 2048 + t * 8;
    int s = 0;
    #pragma unroll
    for (int q = 0; q < 8; q++) { int i = base + q; if (i < n) s += deg[i]; }
    #pragma unroll
    for (int off = 1; off < 64; off <<= 1) s += __shfl_xor(s, off);
    if ((t & 63) == 0) red[t >> 6] = s;
    __syncthreads();
    if (t == 0) bsum[blockIdx.x] = red[0] + red[1] + red[2] + red[3];
}

__global__ void scan_phaseB(int* __restrict__ bsum, int nb) {
    // single wave: exclusive scan over nb (<=64) block sums
    int lane = threadIdx.x & 63;
    int v = (lane < nb) ? bsum[lane] : 0;
    int inc = v;
    #pragma unroll
    for (int off = 1; off < 64; off <<= 1) {
        int u = __shfl_up(inc, off);
        if (lane >= off) inc += u;
    }
    int ex = inc - v;
    if (lane < nb) bsum[lane] = ex;
}

__global__ void scan_phaseC(const int* __restrict__ deg, int n, const int* __restrict__ bsum,
                            int* __restrict__ row_start, int E) {
    __shared__ int wsum[4];
    int t = threadIdx.x;
    int lane = t & 63, wv = t >> 6;
    int base = blockIdx.x * 2048 + t * 8;
    int v[8]; int s = 0;
    #pragma unroll
    for (int q = 0; q < 8; q++) { int i = base + q; v[q] = (i < n) ? deg[i] : 0; s += v[q]; }
    int inc = s;
    #pragma unroll
    for (int off = 1; off < 64; off <<= 1) {
        int u = __shfl_up(inc, off);
        if (lane >= off) inc += u;
    }
    if (lane == 63) wsum[wv] = inc;
    __syncthreads();
    int woff = 0;
    for (int w = 0; w < wv; w++) woff += wsum[w];
    int run = inc - s + woff + bsum[blockIdx.x];
    #pragma unroll
    for (int q = 0; q < 8; q++) {
        int i = base + q;
        if (i < n) row_start[i] = run;
        run += v[q];
    }
    if (blockIdx.x == 0 && t == 0) row_start[n] = E;
}

__global__ void fill_kernel(const int* __restrict__ src, const int* __restrict__ dst, int E,
                            const int* __restrict__ row_start, int* __restrict__ cursor,
                            int* __restrict__ csr_src) {
    int i = blockIdx.x * blockDim.x + threadIdx.x;
    if (i < E) {
        int d = dst[i];
        int pos = atomicAdd(&cursor[d], 1);
        csr_src[row_start[d] + pos] = src[i];
    }
}

// ---------------- weight hi/lo split into PACKED fragment layout ----------------

__global__ void wsplit_all(const float* __restrict__ W1, const float* __restrict__ W2,
                           const float* __restrict__ W3, const float* __restrict__ Wr,
                           _Float16* __restrict__ o) {
    int i = blockIdx.x * blockDim.x + threadIdx.x;
    if (i >= 81920) return;
    float v; int ohi, e, stride;
    if (i < 16384) {
        e = i; int c = e >> 7, k = e & 127;
        v = W1[(size_t)k * 128 + c]; ohi = 0; stride = 16384;
    } else if (i < 32768) {
        e = i - 16384; int c = e >> 7, k = e & 127;
        v = W2[(size_t)k * 128 + c]; ohi = 32768; stride = 16384;
    } else {
        e = i - 32768; int c = e >> 7, k = e & 127;
        v = (c < 192) ? W3[(size_t)k * 192 + c] : Wr[(size_t)k * 192 + (c - 192)];
        ohi = 65536; stride = 49152;
    }
    int c = e >> 7, k = e & 127;
    int po = pack_off(c, k);
    _Float16 hv = (_Float16)v;
    o[ohi + po] = hv;
    o[ohi + stride + po] = (_Float16)(v - (float)hv);
}

// ---------------- x -> packed hi/lo f16 fragment layout ----------------

__global__ void splitx_kernel(const float* __restrict__ x, _Float16* __restrict__ hi,
                              _Float16* __restrict__ lo, int N, int PT) {
    int i = blockIdx.x * blockDim.x + threadIdx.x;
    if (i >= PT * 2048) return;
    int mt = i >> 11, r = i & 2047;
    int q4 = r >> 9, quad = (r >> 7) & 3, ln = (r >> 3) & 15, j = r & 7;
    int n = mt * 16 + ln, k = q4 * 32 + quad * 8 + j;
    float v = (n < N) ? x[(size_t)n * 128 + k] : 0.f;
    _Float16 h = (_Float16)v;
    hi[i] = h;
    lo[i] = (_Float16)(v - (float)h);
}

// ---------------- LDS-free MFMA fc (+ attention logits), layers 1/2 ----------------

template <int CC, int H>
__global__ __launch_bounds__(256, 4) void mfma_fc(
    const _Float16* __restrict__ Ahi, const _Float16* __restrict__ Alo,
    const _Float16* __restrict__ Bhi, const _Float16* __restrict__ Blo,
    const float* __restrict__ al, const float* __restrict__ ar,
    _Float16* __restrict__ feat_out,
    float* __restrict__ el, float* __restrict__ er, int N) {
    constexpr int TILES = CC / 16;
    int t = threadIdx.x;
    int wave = t >> 6, lane = t & 63;
    int ln = lane & 15, quad = lane >> 4;
    int mt = blockIdx.x * 4 + wave;

    f32x4 acc[TILES];
    #pragma unroll
    for (int i = 0; i < TILES; i++) acc[i] = (f32x4){0.f, 0.f, 0.f, 0.f};

    const _Float16* pa_h = Ahi + (size_t)mt * 2048 + lane * 8;
    const _Float16* pa_l = Alo + (size_t)mt * 2048 + lane * 8;

    #pragma unroll
    for (int q4 = 0; q4 < 4; q4++) {
        v8h ah = *(const v8h*)(pa_h + q4 * 512);
        v8h av = *(const v8h*)(pa_l + q4 * 512);
        #pragma unroll
        for (int tt = 0; tt < TILES; tt++) {
            size_t boff = (size_t)tt * 2048 + q4 * 512 + lane * 8;
            v8h bh = *(const v8h*)(Bhi + boff);
            v8h bl = *(const v8h*)(Blo + boff);
            acc[tt] = __builtin_amdgcn_mfma_f32_16x16x32_f16(av, bh, acc[tt], 0, 0, 0);
            acc[tt] = __builtin_amdgcn_mfma_f32_16x16x32_f16(ah, bl, acc[tt], 0, 0, 0);
            acc[tt] = __builtin_amdgcn_mfma_f32_16x16x32_f16(ah, bh, acc[tt], 0, 0, 0);
        }
    }

    #pragma unroll
    for (int tt = 0; tt < TILES; tt++) {
        int n = tt * 16 + ln;
        #pragma unroll
        for (int r = 0; r < 4; r++) {
            int m = mt * 16 + quad * 4 + r;
            if (m < N) feat_out[(size_t)m * CC + n] = (_Float16)acc[tt][r];
        }
    }
    #pragma unroll
    for (int hg = 0; hg < H; hg++) {
        float a0 = al[hg * 32 + ln], a1 = al[hg * 32 + 16 + ln];
        float r0 = ar[hg * 32 + ln], r1 = ar[hg * 32 + 16 + ln];
        #pragma unroll
        for (int r = 0; r < 4; r++) {
            float pl = acc[2 * hg][r] * a0 + acc[2 * hg + 1][r] * a1;
            float pr = acc[2 * hg][r] * r0 + acc[2 * hg + 1][r] * r1;
            #pragma unroll
            for (int off = 1; off < 16; off <<= 1) {
                pl += __shfl_xor(pl, off);
                pr += __shfl_xor(pr, off);
            }
            int m = mt * 16 + quad * 4 + r;
            if (ln == 0 && m < N) {
                el[(size_t)m * H + hg] = pl;
                er[(size_t)m * H + hg] = pr;
            }
        }
    }
}

// ---------------- layer 3: dual grid (y=0: W3 feat f16 + logits; y=1: resW3 fp32) ----------------

__global__ __launch_bounds__(256, 3) void mfma_fc3(
    const _Float16* __restrict__ Ahi, const _Float16* __restrict__ Alo,
    const _Float16* __restrict__ B3h, const _Float16* __restrict__ B3l,
    const _Float16* __restrict__ Brh, const _Float16* __restrict__ Brl,
    const float* __restrict__ al, const float* __restrict__ ar,
    _Float16* __restrict__ feat_out, float* __restrict__ res_out,
    float* __restrict__ el, float* __restrict__ er, int N) {
    constexpr int CC = 192, H = 6, TILES = 12;
    const bool isres = (blockIdx.y == 1);
    const _Float16* __restrict__ Bhi = isres ? Brh : B3h;
    const _Float16* __restrict__ Blo = isres ? Brl : B3l;

    int t = threadIdx.x;
    int wave = t >> 6, lane = t & 63;
    int ln = lane & 15, quad = lane >> 4;
    int mt = blockIdx.x * 4 + wave;

    f32x4 acc[TILES];
    #pragma unroll
    for (int i = 0; i < TILES; i++) acc[i] = (f32x4){0.f, 0.f, 0.f, 0.f};

    const _Float16* pa_h = Ahi + (size_t)mt * 2048 + lane * 8;
    const _Float16* pa_l = Alo + (size_t)mt * 2048 + lane * 8;

    #pragma unroll
    for (int q4 = 0; q4 < 4; q4++) {
        v8h ah = *(const v8h*)(pa_h + q4 * 512);
        v8h av = *(const v8h*)(pa_l + q4 * 512);
        #pragma unroll
        for (int tt = 0; tt < TILES; tt++) {
            size_t boff = (size_t)tt * 2048 + q4 * 512 + lane * 8;
            v8h bh = *(const v8h*)(Bhi + boff);
            v8h bl = *(const v8h*)(Blo + boff);
            acc[tt] = __builtin_amdgcn_mfma_f32_16x16x32_f16(av, bh, acc[tt], 0, 0, 0);
            acc[tt] = __builtin_amdgcn_mfma_f32_16x16x32_f16(ah, bl, acc[tt], 0, 0, 0);
            acc[tt] = __builtin_amdgcn_mfma_f32_16x16x32_f16(ah, bh, acc[tt], 0, 0, 0);
        }
    }

    if (!isres) {
        #pragma unroll
        for (int tt = 0; tt < TILES; tt++) {
            int n = tt * 16 + ln;
            #pragma unroll
            for (int r = 0; r < 4; r++) {
                int m = mt * 16 + quad * 4 + r;
                if (m < N) feat_out[(size_t)m * CC + n] = (_Float16)acc[tt][r];
            }
        }
        #pragma unroll
        for (int hg = 0; hg < H; hg++) {
            float a0 = al[hg * 32 + ln], a1 = al[hg * 32 + 16 + ln];
            float r0 = ar[hg * 32 + ln], r1 = ar[hg * 32 + 16 + ln];
            #pragma unroll
            for (int r = 0; r < 4; r++) {
                float pl = acc[2 * hg][r] * a0 + acc[2 * hg + 1][r] * a1;
                float pr = acc[2 * hg][r] * r0 + acc[2 * hg + 1][r] * r1;
                #pragma unroll
                for (int off = 1; off < 16; off <<= 1) {
                    pl += __shfl_xor(pl, off);
                    pr += __shfl_xor(pr, off);
                }
                int m = mt * 16 + quad * 4 + r;
                if (ln == 0 && m < N) {
                    el[(size_t)m * H + hg] = pl;
                    er[(size_t)m * H + hg] = pr;
                }
            }
        }
    } else {
        #pragma unroll
        for (int tt = 0; tt < TILES; tt++) {
            int n = tt * 16 + ln;
            #pragma unroll
            for (int r = 0; r < 4; r++) {
                int m = mt * 16 + quad * 4 + r;
                if (m < N) res_out[(size_t)m * CC + n] = acc[tt][r];
            }
        }
    }
}

// ---------------- per-node aggregate: ONE WAVE PER NODE, no LDS, no barriers ----------------
// Lane = (edge group g, dim quad d4). Each lane loads csr_src[j] directly (group lanes
// hit the same address -> broadcast). 2x unrolled: two edges' gather chains in flight.
// All shuffles (xor-reduce, head-mean) execute unconditionally; only stores guarded.
// RES: 0 none, 1 packed hi/lo, 2 plain fp32. PACK: emit packed hi/lo planes.

template <int H, bool RELU, bool MEAN, int RES, bool PACK>
__global__ __launch_bounds__(256) void gat_agg_wave(
        const _Float16* __restrict__ feat, const float* __restrict__ el,
        const float* __restrict__ er, const int* __restrict__ row_start,
        const int* __restrict__ csr_src, const float* __restrict__ bias,
        const float* __restrict__ res_plain,
        const _Float16* __restrict__ res_hi, const _Float16* __restrict__ res_lo,
        float* __restrict__ out, _Float16* __restrict__ out_hi, _Float16* __restrict__ out_lo,
        int N) {
    constexpr int ROW = H * 32;
    constexpr int LPG = ROW / 4;          // lanes per edge group (32 for H=4, 48 for H=6)
    constexpr int G   = 64 / LPG;         // edge groups (2 for H=4, 1 for H=6)
    int wv = threadIdx.x >> 6, lane = threadIdx.x & 63;
    int n = blockIdx.x * 4 + wv;
    if (n >= N) return;

    int d4 = lane % LPG;                  // dim quad: dims 4*d4 .. 4*d4+3
    int g  = lane / LPG;                  // edge group (g >= G -> idle in gather)
    int hd = d4 >> 3;                     // head of this lane's dims

    int start = row_start[n], end = row_start[n + 1];
    float er_hd = er[(size_t)n * H + hd];
    const _Float16* fbase = feat + 4 * d4;

    float a0 = 0.f, a1 = 0.f, a2 = 0.f, a3 = 0.f, wsum = 0.f;

    int j = (g < G) ? (start + g) : end;
    for (; j + G < end; j += 2 * G) {
        int s0 = csr_src[j];
        int s1 = csr_src[j + G];
        float e0 = el[(size_t)s0 * H + hd] + er_hd;
        float e1 = el[(size_t)s1 * H + hd] + er_hd;
        e0 = (e0 >= 0.f) ? e0 : 0.2f * e0;
        e1 = (e1 >= 0.f) ? e1 : 0.2f * e1;
        float w0 = __expf(e0);
        float w1 = __expf(e1);
        f16x4 v0 = *(const f16x4*)(fbase + (size_t)s0 * ROW);
        f16x4 v1 = *(const f16x4*)(fbase + (size_t)s1 * ROW);
        wsum += w0 + w1;
        a0 += w0 * (float)v0.x + w1 * (float)v1.x;
        a1 += w0 * (float)v0.y + w1 * (float)v1.y;
        a2 += w0 * (float)v0.z + w1 * (float)v1.z;
        a3 += w0 * (float)v0.w + w1 * (float)v1.w;
    }
    if (j < end) {
        int s0 = csr_src[j];
        float e0 = el[(size_t)s0 * H + hd] + er_hd;
        e0 = (e0 >= 0.f) ? e0 : 0.2f * e0;
        float w0 = __expf(e0);
        f16x4 v0 = *(const f16x4*)(fbase + (size_t)s0 * ROW);
        wsum += w0;
        a0 += w0 * (float)v0.x;
        a1 += w0 * (float)v0.y;
        a2 += w0 * (float)v0.z;
        a3 += w0 * (float)v0.w;
    }

    if constexpr (G == 2) {               // executed by ALL lanes (no divergence)
        a0 += __shfl_xor(a0, 32);
        a1 += __shfl_xor(a1, 32);
        a2 += __shfl_xor(a2, 32);
        a3 += __shfl_xor(a3, 32);
        wsum += __shfl_xor(wsum, 32);
    }

    // epilogue computed by ALL lanes; only stores are guarded.
    float den = fmaxf(wsum, 1e-9f);
    float4 bv = *(const float4*)(bias + 4 * d4);
    float r0 = a0 / den + bv.x;
    float r1 = a1 / den + bv.y;
    float r2 = a2 / den + bv.z;
    float r3 = a3 / den + bv.w;
    if constexpr (RES == 1) {
        int off = pack_off(n, 4 * d4);
        f16x4 rh = *(const f16x4*)(res_hi + off);
        f16x4 rl = *(const f16x4*)(res_lo + off);
        r0 += (float)rh.x + (float)rl.x;
        r1 += (float)rh.y + (float)rl.y;
        r2 += (float)rh.z + (float)rl.z;
        r3 += (float)rh.w + (float)rl.w;
    } else if constexpr (RES == 2) {
        float4 rv = *(const float4*)(res_plain + (size_t)n * ROW + 4 * d4);
        r0 += rv.x; r1 += rv.y; r2 += rv.z; r3 += rv.w;
    }
    if constexpr (RELU) {
        r0 = fmaxf(r0, 0.f); r1 = fmaxf(r1, 0.f);
        r2 = fmaxf(r2, 0.f); r3 = fmaxf(r3, 0.f);
    }

    if constexpr (PACK) {
        if (lane < LPG) {
            int off = pack_off(n, 4 * d4);
            _Float16 h0 = (_Float16)r0, h1 = (_Float16)r1, h2 = (_Float16)r2, h3 = (_Float16)r3;
            *(f16x4*)(out_hi + off) = (f16x4){h0, h1, h2, h3};
            *(f16x4*)(out_lo + off) = (f16x4){(_Float16)(r0 - (float)h0), (_Float16)(r1 - (float)h1),
                                              (_Float16)(r2 - (float)h2), (_Float16)(r3 - (float)h3)};
        }
    } else if constexpr (MEAN) {
        // head-mean: writer lanes (h=0, q<8) need sum over heads hh of lane q+8*hh.
        int q = d4 & 7;
        float s0 = r0, s1 = r1, s2 = r2, s3 = r3;
        #pragma unroll
        for (int hh = 1; hh < H; hh++) {   // executed by ALL lanes
            s0 += __shfl(r0, q + 8 * hh);
            s1 += __shfl(r1, q + 8 * hh);
            s2 += __shfl(r2, q + 8 * hh);
            s3 += __shfl(r3, q + 8 * hh);
        }
        if (lane < 8) {                    // lane==d4==q<8, head 0
            const float sc = 1.0f / H;
            *(float4*)(out + (size_t)n * 32 + 4 * lane) =
                make_float4(s0 * sc, s1 * sc, s2 * sc, s3 * sc);
        }
    } else {
        if (lane < LPG)
            *(float4*)(out + (size_t)n * ROW + 4 * d4) = make_float4(r0, r1, r2, r3);
    }
}

// ---------------- launch ----------------

extern "C" void kernel_launch(void* const* d_in, const int* in_sizes, int n_in,
                              void* d_out, int out_size, void* d_ws, size_t ws_size,
                              hipStream_t stream) {
    const float* x    = (const float*)d_in[0];
    const int*   src  = (const int*)d_in[1];
    const int*   dst  = (const int*)d_in[2];
    const float* W1   = (const float*)d_in[3];
    const float* al1  = (const float*)d_in[4];
    const float* ar1  = (const float*)d_in[5];
    const float* b1   = (const float*)d_in[6];
    const float* W2   = (const float*)d_in[7];
    const float* al2  = (const float*)d_in[8];
    const float* ar2  = (const float*)d_in[9];
    const float* b2   = (const float*)d_in[10];
    const float* W3   = (const float*)d_in[11];
    const float* al3  = (const float*)d_in[12];
    const float* ar3  = (const float*)d_in[13];
    const float* b3   = (const float*)d_in[14];
    const float* resW3= (const float*)d_in[15];
    float* out = (float*)d_out;

    const int N = in_sizes[0] / 128;
    const int E = in_sizes[1];
    const int TILES16 = (N + 15) / 16;
    const int PT = (TILES16 + 3) & ~3;
    const int NB = PT / 4;
    const int NSB = (N + 2047) / 2048;     // scan blocks (<=64 for N<=131072)

    // workspace layout
    float* fws  = (float*)d_ws;
    float* res3 = fws;                          // N*192 fp32
    float* elb  = res3 + (size_t)N * 192;       // N*6
    float* erb  = elb + (size_t)N * 6;          // N*6
    _Float16* feat_h = (_Float16*)(erb + (size_t)N * 6);  // N*192 f16
    _Float16* xh_hi  = feat_h + (size_t)N * 192;          // PT*2048 (x packed; reused as h2)
    _Float16* xh_lo  = xh_hi + (size_t)PT * 2048;
    _Float16* h1_hi  = xh_lo + (size_t)PT * 2048;
    _Float16* h1_lo  = h1_hi + (size_t)PT * 2048;
    _Float16* wts    = h1_lo + (size_t)PT * 2048;         // 163840 f16
    int* deg       = (int*)(wts + 163840);
    int* row_start = deg + N;
    int* bsum      = row_start + (N + 1);
    int* csr_src   = bsum + 64;

    const _Float16* W1h = wts;
    const _Float16* W1l = wts + 16384;
    const _Float16* W2h = wts + 32768;
    const _Float16* W2l = wts + 49152;
    const _Float16* W3h = wts + 65536;
    const _Float16* W3l = wts + 65536 + 49152;
    const _Float16* Wrh = W3h + 192 * 128;
    const _Float16* Wrl = W3l + 192 * 128;

    // ---- CSR build (by dst) + weight split + x packing ----
    hipMemsetAsync(deg, 0, (size_t)N * sizeof(int), stream);
    hist_kernel<<<dim3((E + 255) / 256), dim3(256), 0, stream>>>(dst, E, deg);
    scan_phaseA<<<dim3(NSB), dim3(256), 0, stream>>>(deg, N, bsum);
    scan_phaseB<<<dim3(1), dim3(64), 0, stream>>>(bsum, NSB);
    scan_phaseC<<<dim3(NSB), dim3(256), 0, stream>>>(deg, N, bsum, row_start, E);
    hipMemsetAsync(deg, 0, (size_t)N * sizeof(int), stream);
    fill_kernel<<<dim3((E + 255) / 256), dim3(256), 0, stream>>>(src, dst, E, row_start, deg, csr_src);
    wsplit_all<<<dim3(320), dim3(256), 0, stream>>>(W1, W2, W3, resW3, wts);
    splitx_kernel<<<dim3((PT * 2048 + 255) / 256), dim3(256), 0, stream>>>(x, xh_hi, xh_lo, N, PT);

    dim3 ab((N + 3) / 4);

    // ---- Layer 1 ----
    mfma_fc<128, 4><<<dim3(NB), dim3(256), 0, stream>>>(
        xh_hi, xh_lo, W1h, W1l, al1, ar1, feat_h, elb, erb, N);
    gat_agg_wave<4, true, false, 0, true><<<ab, dim3(256), 0, stream>>>(
        feat_h, elb, erb, row_start, csr_src, b1,
        nullptr, nullptr, nullptr, nullptr, h1_hi, h1_lo, N);

    // ---- Layer 2 (identity residual = h1 packed planes) ----
    mfma_fc<128, 4><<<dim3(NB), dim3(256), 0, stream>>>(
        h1_hi, h1_lo, W2h, W2l, al2, ar2, feat_h, elb, erb, N);
    gat_agg_wave<4, true, false, 1, true><<<ab, dim3(256), 0, stream>>>(
        feat_h, elb, erb, row_start, csr_src, b2,
        nullptr, h1_hi, h1_lo, nullptr, xh_hi, xh_lo, N);   // h2 -> reuse x planes

    // ---- Layer 3: dual GEMM, then mean-agg ----
    mfma_fc3<<<dim3(NB, 2), dim3(256), 0, stream>>>(
        xh_hi, xh_lo, W3h, W3l, Wrh, Wrl, al3, ar3, feat_h, res3, elb, erb, N);
    gat_agg_wave<6, false, true, 2, false><<<ab, dim3(256), 0, stream>>>(
        feat_h, elb, erb, row_start, csr_src, b3,
        res3, nullptr, nullptr, out, nullptr, nullptr, N);
}

// Round 12
// 424.522 us; speedup vs baseline: 1.9692x; 1.0509x over previous
//
#include <hip/hip_runtime.h>
#include <math.h>

// GAT 3-layer forward on MI355X.
// N=50000 nodes, E=850000 edges (incl self loops), IN=128, HID=OUT=32, HEADS=(4,4,6).
// GEMMs: split-f16 MFMA (hi/lo, 3 mfma), LDS-free; A and B pre-packed in MFMA-fragment
// order (pack_off) -> every wave load is 1KB contiguous. NEVER partial-unroll the tile
// loop (dynamic acc[] indexing -> scratch spill, round 4).
// Aggregation: ONE WAVE PER NODE, zero LDS, zero barriers; f16x8 (16B) gathers, 8 dims
// per lane -> 4 edge groups for ROW=128 (all 64 lanes), 2 groups for ROW=192. All
// cross-lane shuffles execute unconditionally (round 9 lesson); stores guarded.
// CSR prefix scan: 3-phase multi-block (round 10's single-block scan was 77us on 1 CU).

typedef _Float16 v8h __attribute__((ext_vector_type(8)));
typedef float f32x4 __attribute__((ext_vector_type(4)));

// packed fragment offset for row n, k-dim k (128-wide K):
__device__ __host__ inline int pack_off(int n, int k) {
    return ((n >> 4) << 11) | ((k >> 5) << 9) | (((k >> 3) & 3) << 7) | ((n & 15) << 3) | (k & 7);
}

// ---------------- CSR build (by dst) ----------------

__global__ void hist_kernel(const int* __restrict__ dst, int E, int* __restrict__ deg) {
    int i = blockIdx.x * blockDim.x + threadIdx.x;
    if (i < E) atomicAdd(&deg[dst[i]], 1);
}

// ---- 3-phase exclusive scan of deg[n] -> row_start (2048 elems per block) ----

__global__ void scan_phaseA(const int* __restrict__ deg, int n, int* __restrict__ bsum) {
    __shared__ int red[4];
    int t = threadIdx.x;
    int base = blockIdx.x * 2048 + t * 8;
    int s = 0;
    #pragma unroll
    for (int q = 0; q < 8; q++) { int i = base + q; if (i < n) s += deg[i]; }
    #pragma unroll
    for (int off = 1; off < 64; off <<= 1) s += __shfl_xor(s, off);
    if ((t & 63) == 0) red[t >> 6] = s;
    __syncthreads();
    if (t == 0) bsum[blockIdx.x] = red[0] + red[1] + red[2] + red[3];
}

__global__ void scan_phaseB(int* __restrict__ bsum, int nb) {
    int lane = threadIdx.x & 63;
    int v = (lane < nb) ? bsum[lane] : 0;
    int inc = v;
    #pragma unroll
    for (int off = 1; off < 64; off <<= 1) {
        int u = __shfl_up(inc, off);
        if (lane >= off) inc += u;
    }
    int ex = inc - v;
    if (lane < nb) bsum[lane] = ex;
}

__global__ void scan_phaseC(const int* __restrict__ deg, int n, const int* __restrict__ bsum,
                            int* __restrict__ row_start, int E) {
    __shared__ int wsum[4];
    int t = threadIdx.x;
    int lane = t & 63, wv = t >> 6;
    int base = blockIdx.x * 2048 + t * 8;
    int v[8]; int s = 0;
    #pragma unroll
    for (int q = 0; q < 8; q++) { int i = base + q; v[q] = (i < n) ? deg[i] : 0; s += v[q]; }
    int inc = s;
    #pragma unroll
    for (int off = 1; off < 64; off <<= 1) {
        int u = __shfl_up(inc, off);
        if (lane >= off) inc += u;
    }
    if (lane == 63) wsum[wv] = inc;
    __syncthreads();
    int woff = 0;
    for (int w = 0; w < wv; w++) woff += wsum[w];
    int run = inc - s + woff + bsum[blockIdx.x];
    #pragma unroll
    for (int q = 0; q < 8; q++) {
        int i = base + q;
        if (i < n) row_start[i] = run;
        run += v[q];
    }
    if (blockIdx.x == 0 && t == 0) row_start[n] = E;
}

__global__ void fill_kernel(const int* __restrict__ src, const int* __restrict__ dst, int E,
                            const int* __restrict__ row_start, int* __restrict__ cursor,
                            int* __restrict__ csr_src) {
    int i = blockIdx.x * blockDim.x + threadIdx.x;
    if (i < E) {
        int d = dst[i];
        int pos = atomicAdd(&cursor[d], 1);
        csr_src[row_start[d] + pos] = src[i];
    }
}

// ---------------- weight hi/lo split into PACKED fragment layout ----------------

__global__ void wsplit_all(const float* __restrict__ W1, const float* __restrict__ W2,
                           const float* __restrict__ W3, const float* __restrict__ Wr,
                           _Float16* __restrict__ o) {
    int i = blockIdx.x * blockDim.x + threadIdx.x;
    if (i >= 81920) return;
    float v; int ohi, e, stride;
    if (i < 16384) {
        e = i; int c = e >> 7, k = e & 127;
        v = W1[(size_t)k * 128 + c]; ohi = 0; stride = 16384;
    } else if (i < 32768) {
        e = i - 16384; int c = e >> 7, k = e & 127;
        v = W2[(size_t)k * 128 + c]; ohi = 32768; stride = 16384;
    } else {
        e = i - 32768; int c = e >> 7, k = e & 127;
        v = (c < 192) ? W3[(size_t)k * 192 + c] : Wr[(size_t)k * 192 + (c - 192)];
        ohi = 65536; stride = 49152;
    }
    int c = e >> 7, k = e & 127;
    int po = pack_off(c, k);
    _Float16 hv = (_Float16)v;
    o[ohi + po] = hv;
    o[ohi + stride + po] = (_Float16)(v - (float)hv);
}

// ---------------- x -> packed hi/lo f16 fragment layout ----------------

__global__ void splitx_kernel(const float* __restrict__ x, _Float16* __restrict__ hi,
                              _Float16* __restrict__ lo, int N, int PT) {
    int i = blockIdx.x * blockDim.x + threadIdx.x;
    if (i >= PT * 2048) return;
    int mt = i >> 11, r = i & 2047;
    int q4 = r >> 9, quad = (r >> 7) & 3, ln = (r >> 3) & 15, j = r & 7;
    int n = mt * 16 + ln, k = q4 * 32 + quad * 8 + j;
    float v = (n < N) ? x[(size_t)n * 128 + k] : 0.f;
    _Float16 h = (_Float16)v;
    hi[i] = h;
    lo[i] = (_Float16)(v - (float)h);
}

// ---------------- LDS-free MFMA fc (+ attention logits), layers 1/2 ----------------

template <int CC, int H>
__global__ __launch_bounds__(256, 4) void mfma_fc(
    const _Float16* __restrict__ Ahi, const _Float16* __restrict__ Alo,
    const _Float16* __restrict__ Bhi, const _Float16* __restrict__ Blo,
    const float* __restrict__ al, const float* __restrict__ ar,
    _Float16* __restrict__ feat_out,
    float* __restrict__ el, float* __restrict__ er, int N) {
    constexpr int TILES = CC / 16;
    int t = threadIdx.x;
    int wave = t >> 6, lane = t & 63;
    int ln = lane & 15, quad = lane >> 4;
    int mt = blockIdx.x * 4 + wave;

    f32x4 acc[TILES];
    #pragma unroll
    for (int i = 0; i < TILES; i++) acc[i] = (f32x4){0.f, 0.f, 0.f, 0.f};

    const _Float16* pa_h = Ahi + (size_t)mt * 2048 + lane * 8;
    const _Float16* pa_l = Alo + (size_t)mt * 2048 + lane * 8;

    #pragma unroll
    for (int q4 = 0; q4 < 4; q4++) {
        v8h ah = *(const v8h*)(pa_h + q4 * 512);
        v8h av = *(const v8h*)(pa_l + q4 * 512);
        #pragma unroll
        for (int tt = 0; tt < TILES; tt++) {
            size_t boff = (size_t)tt * 2048 + q4 * 512 + lane * 8;
            v8h bh = *(const v8h*)(Bhi + boff);
            v8h bl = *(const v8h*)(Blo + boff);
            acc[tt] = __builtin_amdgcn_mfma_f32_16x16x32_f16(av, bh, acc[tt], 0, 0, 0);
            acc[tt] = __builtin_amdgcn_mfma_f32_16x16x32_f16(ah, bl, acc[tt], 0, 0, 0);
            acc[tt] = __builtin_amdgcn_mfma_f32_16x16x32_f16(ah, bh, acc[tt], 0, 0, 0);
        }
    }

    #pragma unroll
    for (int tt = 0; tt < TILES; tt++) {
        int n = tt * 16 + ln;
        #pragma unroll
        for (int r = 0; r < 4; r++) {
            int m = mt * 16 + quad * 4 + r;
            if (m < N) feat_out[(size_t)m * CC + n] = (_Float16)acc[tt][r];
        }
    }
    #pragma unroll
    for (int hg = 0; hg < H; hg++) {
        float a0 = al[hg * 32 + ln], a1 = al[hg * 32 + 16 + ln];
        float r0 = ar[hg * 32 + ln], r1 = ar[hg * 32 + 16 + ln];
        #pragma unroll
        for (int r = 0; r < 4; r++) {
            float pl = acc[2 * hg][r] * a0 + acc[2 * hg + 1][r] * a1;
            float pr = acc[2 * hg][r] * r0 + acc[2 * hg + 1][r] * r1;
            #pragma unroll
            for (int off = 1; off < 16; off <<= 1) {
                pl += __shfl_xor(pl, off);
                pr += __shfl_xor(pr, off);
            }
            int m = mt * 16 + quad * 4 + r;
            if (ln == 0 && m < N) {
                el[(size_t)m * H + hg] = pl;
                er[(size_t)m * H + hg] = pr;
            }
        }
    }
}

// ---------------- layer 3: dual grid (y=0: W3 feat f16 + logits; y=1: resW3 fp32) ----------------

__global__ __launch_bounds__(256, 3) void mfma_fc3(
    const _Float16* __restrict__ Ahi, const _Float16* __restrict__ Alo,
    const _Float16* __restrict__ B3h, const _Float16* __restrict__ B3l,
    const _Float16* __restrict__ Brh, const _Float16* __restrict__ Brl,
    const float* __restrict__ al, const float* __restrict__ ar,
    _Float16* __restrict__ feat_out, float* __restrict__ res_out,
    float* __restrict__ el, float* __restrict__ er, int N) {
    constexpr int CC = 192, H = 6, TILES = 12;
    const bool isres = (blockIdx.y == 1);
    const _Float16* __restrict__ Bhi = isres ? Brh : B3h;
    const _Float16* __restrict__ Blo = isres ? Brl : B3l;

    int t = threadIdx.x;
    int wave = t >> 6, lane = t & 63;
    int ln = lane & 15, quad = lane >> 4;
    int mt = blockIdx.x * 4 + wave;

    f32x4 acc[TILES];
    #pragma unroll
    for (int i = 0; i < TILES; i++) acc[i] = (f32x4){0.f, 0.f, 0.f, 0.f};

    const _Float16* pa_h = Ahi + (size_t)mt * 2048 + lane * 8;
    const _Float16* pa_l = Alo + (size_t)mt * 2048 + lane * 8;

    #pragma unroll
    for (int q4 = 0; q4 < 4; q4++) {
        v8h ah = *(const v8h*)(pa_h + q4 * 512);
        v8h av = *(const v8h*)(pa_l + q4 * 512);
        #pragma unroll
        for (int tt = 0; tt < TILES; tt++) {
            size_t boff = (size_t)tt * 2048 + q4 * 512 + lane * 8;
            v8h bh = *(const v8h*)(Bhi + boff);
            v8h bl = *(const v8h*)(Blo + boff);
            acc[tt] = __builtin_amdgcn_mfma_f32_16x16x32_f16(av, bh, acc[tt], 0, 0, 0);
            acc[tt] = __builtin_amdgcn_mfma_f32_16x16x32_f16(ah, bl, acc[tt], 0, 0, 0);
            acc[tt] = __builtin_amdgcn_mfma_f32_16x16x32_f16(ah, bh, acc[tt], 0, 0, 0);
        }
    }

    if (!isres) {
        #pragma unroll
        for (int tt = 0; tt < TILES; tt++) {
            int n = tt * 16 + ln;
            #pragma unroll
            for (int r = 0; r < 4; r++) {
                int m = mt * 16 + quad * 4 + r;
                if (m < N) feat_out[(size_t)m * CC + n] = (_Float16)acc[tt][r];
            }
        }
        #pragma unroll
        for (int hg = 0; hg < H; hg++) {
            float a0 = al[hg * 32 + ln], a1 = al[hg * 32 + 16 + ln];
            float r0 = ar[hg * 32 + ln], r1 = ar[hg * 32 + 16 + ln];
            #pragma unroll
            for (int r = 0; r < 4; r++) {
                float pl = acc[2 * hg][r] * a0 + acc[2 * hg + 1][r] * a1;
                float pr = acc[2 * hg][r] * r0 + acc[2 * hg + 1][r] * r1;
                #pragma unroll
                for (int off = 1; off < 16; off <<= 1) {
                    pl += __shfl_xor(pl, off);
                    pr += __shfl_xor(pr, off);
                }
                int m = mt * 16 + quad * 4 + r;
                if (ln == 0 && m < N) {
                    el[(size_t)m * H + hg] = pl;
                    er[(size_t)m * H + hg] = pr;
                }
            }
        }
    } else {
        #pragma unroll
        for (int tt = 0; tt < TILES; tt++) {
            int n = tt * 16 + ln;
            #pragma unroll
            for (int r = 0; r < 4; r++) {
                int m = mt * 16 + quad * 4 + r;
                if (m < N) res_out[(size_t)m * CC + n] = acc[tt][r];
            }
        }
    }
}

// ---------------- per-node aggregate: ONE WAVE PER NODE, f16x8 gathers ----------------
// Lane = (edge group g, dim-octet d8: dims 8*d8..8*d8+7; head = d8>>2, no boundary
// crossing). ROW=128: LPG=16, G=4 (all 64 lanes). ROW=192: LPG=24, G=2 (48 lanes).
// 2x unrolled loop -> 2*G edges in flight. All shuffles unconditional; stores guarded.
// RES: 0 none, 1 packed hi/lo, 2 plain fp32. PACK: emit packed hi/lo planes.

template <int H, bool RELU, bool MEAN, int RES, bool PACK>
__global__ __launch_bounds__(256) void gat_agg_wave(
        const _Float16* __restrict__ feat, const float* __restrict__ el,
        const float* __restrict__ er, const int* __restrict__ row_start,
        const int* __restrict__ csr_src, const float* __restrict__ bias,
        const float* __restrict__ res_plain,
        const _Float16* __restrict__ res_hi, const _Float16* __restrict__ res_lo,
        float* __restrict__ out, _Float16* __restrict__ out_hi, _Float16* __restrict__ out_lo,
        int N) {
    constexpr int ROW = H * 32;
    constexpr int LPG = ROW / 8;          // lanes per edge group (16 for H=4, 24 for H=6)
    constexpr int G   = 64 / LPG;         // edge groups (4 for H=4, 2 for H=6)
    int wv = threadIdx.x >> 6, lane = threadIdx.x & 63;
    int n = blockIdx.x * 4 + wv;
    if (n >= N) return;

    int d8 = lane % LPG;                  // dim octet: dims 8*d8 .. 8*d8+7
    int g  = lane / LPG;                  // edge group (g >= G -> idle in gather)
    int hd = d8 >> 2;                     // head of this lane's dims (4 lanes per head)

    int start = row_start[n], end = row_start[n + 1];
    float er_hd = er[(size_t)n * H + hd];
    const _Float16* fbase = feat + 8 * d8;

    float acc[8];
    #pragma unroll
    for (int q = 0; q < 8; q++) acc[q] = 0.f;
    float wsum = 0.f;

    int j = (g < G) ? (start + g) : end;
    for (; j + G < end; j += 2 * G) {
        int s0 = csr_src[j];
        int s1 = csr_src[j + G];
        float e0 = el[(size_t)s0 * H + hd] + er_hd;
        float e1 = el[(size_t)s1 * H + hd] + er_hd;
        e0 = (e0 >= 0.f) ? e0 : 0.2f * e0;
        e1 = (e1 >= 0.f) ? e1 : 0.2f * e1;
        float w0 = __expf(e0);
        float w1 = __expf(e1);
        v8h v0 = *(const v8h*)(fbase + (size_t)s0 * ROW);
        v8h v1 = *(const v8h*)(fbase + (size_t)s1 * ROW);
        wsum += w0 + w1;
        #pragma unroll
        for (int q = 0; q < 8; q++) acc[q] += w0 * (float)v0[q] + w1 * (float)v1[q];
    }
    if (j < end) {
        int s0 = csr_src[j];
        float e0 = el[(size_t)s0 * H + hd] + er_hd;
        e0 = (e0 >= 0.f) ? e0 : 0.2f * e0;
        float w0 = __expf(e0);
        v8h v0 = *(const v8h*)(fbase + (size_t)s0 * ROW);
        wsum += w0;
        #pragma unroll
        for (int q = 0; q < 8; q++) acc[q] += w0 * (float)v0[q];
    }

    // cross-group combine (executed by ALL lanes; results valid for lanes < LPG)
    if constexpr (G == 4) {
        #pragma unroll
        for (int q = 0; q < 8; q++) {
            acc[q] += __shfl_xor(acc[q], 16);
            acc[q] += __shfl_xor(acc[q], 32);
        }
        wsum += __shfl_xor(wsum, 16);
        wsum += __shfl_xor(wsum, 32);
    } else {  // G == 2, LPG == 24: partner lane +24
        #pragma unroll
        for (int q = 0; q < 8; q++) acc[q] += __shfl(acc[q], lane + 24);
        wsum += __shfl(wsum, lane + 24);
    }

    // epilogue computed by ALL lanes; only stores guarded.
    float inv = 1.0f / fmaxf(wsum, 1e-9f);
    float4 bv0 = *(const float4*)(bias + 8 * d8);
    float4 bv1 = *(const float4*)(bias + 8 * d8 + 4);
    float r[8];
    r[0] = acc[0] * inv + bv0.x; r[1] = acc[1] * inv + bv0.y;
    r[2] = acc[2] * inv + bv0.z; r[3] = acc[3] * inv + bv0.w;
    r[4] = acc[4] * inv + bv1.x; r[5] = acc[5] * inv + bv1.y;
    r[6] = acc[6] * inv + bv1.z; r[7] = acc[7] * inv + bv1.w;

    if constexpr (RES == 1) {
        int off = pack_off(n, 8 * d8);
        v8h rh = *(const v8h*)(res_hi + off);
        v8h rl = *(const v8h*)(res_lo + off);
        #pragma unroll
        for (int q = 0; q < 8; q++) r[q] += (float)rh[q] + (float)rl[q];
    } else if constexpr (RES == 2) {
        float4 rv0 = *(const float4*)(res_plain + (size_t)n * ROW + 8 * d8);
        float4 rv1 = *(const float4*)(res_plain + (size_t)n * ROW + 8 * d8 + 4);
        r[0] += rv0.x; r[1] += rv0.y; r[2] += rv0.z; r[3] += rv0.w;
        r[4] += rv1.x; r[5] += rv1.y; r[6] += rv1.z; r[7] += rv1.w;
    }
    if constexpr (RELU) {
        #pragma unroll
        for (int q = 0; q < 8; q++) r[q] = fmaxf(r[q], 0.f);
    }

    if constexpr (PACK) {
        if (lane < LPG) {
            int off = pack_off(n, 8 * d8);
            v8h hh, ll;
            #pragma unroll
            for (int q = 0; q < 8; q++) {
                hh[q] = (_Float16)r[q];
                ll[q] = (_Float16)(r[q] - (float)hh[q]);
            }
            *(v8h*)(out_hi + off) = hh;
            *(v8h*)(out_lo + off) = ll;
        }
    } else if constexpr (MEAN) {
        // head-mean: lane d8 = h*4 + qb holds dims h*32 + 8*qb ..; writers lanes 0..3.
        int qb = d8 & 3;
        float s[8];
        #pragma unroll
        for (int q = 0; q < 8; q++) {
            s[q] = r[q];
            #pragma unroll
            for (int hh2 = 1; hh2 < H; hh2++) s[q] += __shfl(r[q], qb + 4 * hh2);
        }
        if (lane < 4) {
            const float sc = 1.0f / H;
            *(float4*)(out + (size_t)n * 32 + 8 * lane) =
                make_float4(s[0] * sc, s[1] * sc, s[2] * sc, s[3] * sc);
            *(float4*)(out + (size_t)n * 32 + 8 * lane + 4) =
                make_float4(s[4] * sc, s[5] * sc, s[6] * sc, s[7] * sc);
        }
    } else {
        if (lane < LPG) {
            *(float4*)(out + (size_t)n * ROW + 8 * d8) = make_float4(r[0], r[1], r[2], r[3]);
            *(float4*)(out + (size_t)n * ROW + 8 * d8 + 4) = make_float4(r[4], r[5], r[6], r[7]);
        }
    }
}

// ---------------- launch ----------------

extern "C" void kernel_launch(void* const* d_in, const int* in_sizes, int n_in,
                              void* d_out, int out_size, void* d_ws, size_t ws_size,
                              hipStream_t stream) {
    const float* x    = (const float*)d_in[0];
    const int*   src  = (const int*)d_in[1];
    const int*   dst  = (const int*)d_in[2];
    const float* W1   = (const float*)d_in[3];
    const float* al1  = (const float*)d_in[4];
    const float* ar1  = (const float*)d_in[5];
    const float* b1   = (const float*)d_in[6];
    const float* W2   = (const float*)d_in[7];
    const float* al2  = (const float*)d_in[8];
    const float* ar2  = (const float*)d_in[9];
    const float* b2   = (const float*)d_in[10];
    const float* W3   = (const float*)d_in[11];
    const float* al3  = (const float*)d_in[12];
    const float* ar3  = (const float*)d_in[13];
    const float* b3   = (const float*)d_in[14];
    const float* resW3= (const float*)d_in[15];
    float* out = (float*)d_out;

    const int N = in_sizes[0] / 128;
    const int E = in_sizes[1];
    const int TILES16 = (N + 15) / 16;
    const int PT = (TILES16 + 3) & ~3;
    const int NB = PT / 4;
    const int NSB = (N + 2047) / 2048;     // scan blocks (<=64 for N<=131072)

    // workspace layout
    float* fws  = (float*)d_ws;
    float* res3 = fws;                          // N*192 fp32
    float* elb  = res3 + (size_t)N * 192;       // N*6
    float* erb  = elb + (size_t)N * 6;          // N*6
    _Float16* feat_h = (_Float16*)(erb + (size_t)N * 6);  // N*192 f16
    _Float16* xh_hi  = feat_h + (size_t)N * 192;          // PT*2048 (x packed; reused as h2)
    _Float16* xh_lo  = xh_hi + (size_t)PT * 2048;
    _Float16* h1_hi  = xh_lo + (size_t)PT * 2048;
    _Float16* h1_lo  = h1_hi + (size_t)PT * 2048;
    _Float16* wts    = h1_lo + (size_t)PT * 2048;         // 163840 f16
    int* deg       = (int*)(wts + 163840);
    int* row_start = deg + N;
    int* bsum      = row_start + (N + 1);
    int* csr_src   = bsum + 64;

    const _Float16* W1h = wts;
    const _Float16* W1l = wts + 16384;
    const _Float16* W2h = wts + 32768;
    const _Float16* W2l = wts + 49152;
    const _Float16* W3h = wts + 65536;
    const _Float16* W3l = wts + 65536 + 49152;
    const _Float16* Wrh = W3h + 192 * 128;
    const _Float16* Wrl = W3l + 192 * 128;

    // ---- CSR build (by dst) + weight split + x packing ----
    hipMemsetAsync(deg, 0, (size_t)N * sizeof(int), stream);
    hist_kernel<<<dim3((E + 255) / 256), dim3(256), 0, stream>>>(dst, E, deg);
    scan_phaseA<<<dim3(NSB), dim3(256), 0, stream>>>(deg, N, bsum);
    scan_phaseB<<<dim3(1), dim3(64), 0, stream>>>(bsum, NSB);
    scan_phaseC<<<dim3(NSB), dim3(256), 0, stream>>>(deg, N, bsum, row_start, E);
    hipMemsetAsync(deg, 0, (size_t)N * sizeof(int), stream);
    fill_kernel<<<dim3((E + 255) / 256), dim3(256), 0, stream>>>(src, dst, E, row_start, deg, csr_src);
    wsplit_all<<<dim3(320), dim3(256), 0, stream>>>(W1, W2, W3, resW3, wts);
    splitx_kernel<<<dim3((PT * 2048 + 255) / 256), dim3(256), 0, stream>>>(x, xh_hi, xh_lo, N, PT);

    dim3 ab((N + 3) / 4);

    // ---- Layer 1 ----
    mfma_fc<128, 4><<<dim3(NB), dim3(256), 0, stream>>>(
        xh_hi, xh_lo, W1h, W1l, al1, ar1, feat_h, elb, erb, N);
    gat_agg_wave<4, true, false, 0, true><<<ab, dim3(256), 0, stream>>>(
        feat_h, elb, erb, row_start, csr_src, b1,
        nullptr, nullptr, nullptr, nullptr, h1_hi, h1_lo, N);

    // ---- Layer 2 (identity residual = h1 packed planes) ----
    mfma_fc<128, 4><<<dim3(NB), dim3(256), 0, stream>>>(
        h1_hi, h1_lo, W2h, W2l, al2, ar2, feat_h, elb, erb, N);
    gat_agg_wave<4, true, false, 1, true><<<ab, dim3(256), 0, stream>>>(
        feat_h, elb, erb, row_start, csr_src, b2,
        nullptr, h1_hi, h1_lo, nullptr, xh_hi, xh_lo, N);   // h2 -> reuse x planes

    // ---- Layer 3: dual GEMM, then mean-agg ----
    mfma_fc3<<<dim3(NB, 2), dim3(256), 0, stream>>>(
        xh_hi, xh_lo, W3h, W3l, Wrh, Wrl, al3, ar3, feat_h, res3, elb, erb, N);
    gat_agg_wave<6, false, true, 2, false><<<ab, dim3(256), 0, stream>>>(
        feat_h, elb, erb, row_start, csr_src, b3,
        res3, nullptr, nullptr, out, nullptr, nullptr, N);
}